// Round 1
// baseline (75.117 us; speedup 1.0000x reference)
//
#include <hip/hip_runtime.h>
#include <hip/hip_bf16.h>
#include <math.h>

typedef __bf16 bf16;
typedef __attribute__((ext_vector_type(2))) __bf16 bf16x2;
typedef __attribute__((ext_vector_type(4))) __bf16 bf16x4;
typedef __attribute__((ext_vector_type(8))) __bf16 bf16x8;
typedef __attribute__((ext_vector_type(4))) float f32x4;

#define T_DIM 1024
#define C_DIM 256
#define HEADS 8
#define DQK 64
#define DV 32

// XOR swizzles on 16B granules. swz4: rows of 32 bf16 (64B, 4 granules).
// swz8: rows of 64 bf16 (128B, 8 granules). Spread same-granule column
// reads across banks (G4: row-major tiles are 8/16-way conflicts otherwise).
static __device__ __forceinline__ int swz4(int row, int g) { return row * 64 + ((g ^ (row & 3)) << 4); }
static __device__ __forceinline__ int swz8(int row, int g) { return row * 128 + ((g ^ (row & 7)) << 4); }

// ---------------- kernel 0: x (n,256,1024) f32 -> xT (n,1024,256) bf16 ----------------
__global__ __launch_bounds__(256) void k_transpose(const float* __restrict__ x, bf16* __restrict__ xT) {
  __shared__ float tile[64][65];
  const int n = blockIdx.z;
  const int ct = blockIdx.y * 64;
  const int tt = blockIdx.x * 64;
  const float* xp = x + (size_t)n * C_DIM * T_DIM;
  const int t = threadIdx.x & 63;
  const int c0 = threadIdx.x >> 6;
#pragma unroll
  for (int i = 0; i < 16; ++i) {
    int c = c0 + i * 4;
    tile[c][t] = xp[(size_t)(ct + c) * T_DIM + tt + t];
  }
  __syncthreads();
  const int c2 = (threadIdx.x & 31) * 2;
  const int tr0 = threadIdx.x >> 5;
#pragma unroll
  for (int i = 0; i < 8; ++i) {
    int tr = tr0 + i * 8;
    bf16x2 u;
    u[0] = (bf16)tile[c2][tr];
    u[1] = (bf16)tile[c2 + 1][tr];
    *(bf16x2*)(xT + ((size_t)n * T_DIM + tt + tr) * C_DIM + ct + c2) = u;
  }
}

// ---------------- kernel 1: QKV projection ----------------
// C[o][t] = sum_c W[o][c] * x[n][c][t] + bias[o], W = [Wq; Wkv] (1280 rows)
// A-frag: W rows (c-contig), B-frag: xT rows (c-contig). MFMA 16x16x32 bf16.
// Epilogue: lane holds 4 consecutive o-rows at fixed t (C/D layout m89).
__global__ __launch_bounds__(256) void k_qkv(const bf16* __restrict__ xT,
    const float* __restrict__ Wq, const float* __restrict__ bq,
    const float* __restrict__ Wkv, const float* __restrict__ bkv,
    bf16* __restrict__ q_ws, bf16* __restrict__ k_ws, bf16* __restrict__ vT_ws) {
  __shared__ __attribute__((aligned(16))) unsigned char lds[8192]; // A[64][32] | B[64][32] bf16 swizzled
  const int tid = threadIdx.x;
  const int n = blockIdx.z;
  const int o0 = blockIdx.y * 64;
  const int tt = blockIdx.x * 64;
  const int w = tid >> 6, lane = tid & 63;
  const int lrow = lane & 15, lg = lane >> 4;

  const int srow = tid >> 2;   // 0..63
  const int sg = tid & 3;      // granule (8 elems)
  const int oa = o0 + srow;
  const float* wrow = (oa < 512) ? (Wq + (size_t)oa * C_DIM) : (Wkv + (size_t)(oa - 512) * C_DIM);
  const bf16* xrow = xT + ((size_t)n * T_DIM + tt + srow) * C_DIM;

  f32x4 acc[4] = {{0.f,0.f,0.f,0.f},{0.f,0.f,0.f,0.f},{0.f,0.f,0.f,0.f},{0.f,0.f,0.f,0.f}};
#pragma unroll 1
  for (int kk = 0; kk < 8; ++kk) {
    const float* ap = wrow + kk * 32 + sg * 8;
    float4 a01 = *(const float4*)ap;
    float4 a23 = *(const float4*)(ap + 4);
    bf16x8 av;
    av[0] = (bf16)a01.x; av[1] = (bf16)a01.y; av[2] = (bf16)a01.z; av[3] = (bf16)a01.w;
    av[4] = (bf16)a23.x; av[5] = (bf16)a23.y; av[6] = (bf16)a23.z; av[7] = (bf16)a23.w;
    *(bf16x8*)(lds + swz4(srow, sg)) = av;
    bf16x8 bv = *(const bf16x8*)(xrow + kk * 32 + sg * 8);
    *(bf16x8*)(lds + 4096 + swz4(srow, sg)) = bv;
    __syncthreads();
    bf16x8 af = *(const bf16x8*)(lds + swz4(w * 16 + lrow, lg));
#pragma unroll
    for (int ct = 0; ct < 4; ++ct) {
      bf16x8 bfv = *(const bf16x8*)(lds + 4096 + swz4(ct * 16 + lrow, lg));
      acc[ct] = __builtin_amdgcn_mfma_f32_16x16x32_bf16(af, bfv, acc[ct], 0, 0, 0);
    }
    __syncthreads();
  }

  // epilogue: o rows = o0 + 16w + 4*lg + r, t col = tt + 16*ct + lrow
  const int of = o0 + w * 16 + lg * 4;
  const int nhb = n * HEADS;
#pragma unroll
  for (int ct = 0; ct < 4; ++ct) {
    const int t = tt + ct * 16 + lrow;
    if (of < 512) {            // Q: head = of/64, d = of%64 -> q_ws[n,h,t,d]
      const int head = of >> 6, d = of & 63;
      bf16x4 pk;
#pragma unroll
      for (int r = 0; r < 4; ++r) pk[r] = (bf16)(acc[ct][r] + bq[of + r]);
      *(bf16x4*)(q_ws + (((size_t)(nhb + head)) * T_DIM + t) * DQK + d) = pk;
    } else if (of < 1024) {    // K
      const int o2 = of - 512;
      const int head = o2 >> 6, d = o2 & 63;
      bf16x4 pk;
#pragma unroll
      for (int r = 0; r < 4; ++r) pk[r] = (bf16)(acc[ct][r] + bkv[o2 + r]);
      *(bf16x4*)(k_ws + (((size_t)(nhb + head)) * T_DIM + t) * DQK + d) = pk;
    } else {                   // V -> transposed layout vT[n,h,dv,s]
      const int o3 = of - 1024;
      const int head = o3 >> 5, dv = o3 & 31;
#pragma unroll
      for (int r = 0; r < 4; ++r)
        vT_ws[(((size_t)(nhb + head)) * DV + dv + r) * T_DIM + t] = (bf16)(acc[ct][r] + bkv[of - 512 + r]);
    }
  }
}

// ---------------- kernel 2: causal attention ----------------
// Per (n,h): S^T = K*Q^T (softmax stats lane-local at t=lane&15),
// P -> per-wave LDS, O^T = Vt * P^T. Online softmax. Output attT[n,t,h*32+dv].
__global__ __launch_bounds__(256) void k_attn(const bf16* __restrict__ q_ws,
    const bf16* __restrict__ k_ws, const bf16* __restrict__ vT_ws,
    bf16* __restrict__ attT) {
  __shared__ __attribute__((aligned(16))) unsigned char Klds[8192]; // [64 s][64 d] swizzled
  __shared__ __attribute__((aligned(16))) unsigned char Vlds[4096]; // [32 dv][64 s] swizzled
  __shared__ __attribute__((aligned(16))) unsigned char Plds[8192]; // 4 waves x [16 t][64 s]
  const int tid = threadIdx.x;
  const int qt = blockIdx.x;   // q tile 0..15
  const int nh = blockIdx.y;   // 0..63
  const int w = tid >> 6, lane = tid & 63;
  const int lrow = lane & 15, lg = lane >> 4;
  const int tg = qt * 64 + w * 16 + lrow; // this lane's t (column)

  const bf16* qbase = q_ws + ((size_t)nh * T_DIM + tg) * DQK;
  bf16x8 qf0 = *(const bf16x8*)(qbase + lg * 8);
  bf16x8 qf1 = *(const bf16x8*)(qbase + 32 + lg * 8);

  const bf16* kbase = k_ws + (size_t)nh * T_DIM * DQK;
  const bf16* vbase = vT_ws + (size_t)nh * DV * T_DIM;
  unsigned char* pw = Plds + w * 2048;

  float m = -INFINITY, l = 0.f;
  f32x4 oacc[2] = {{0.f,0.f,0.f,0.f},{0.f,0.f,0.f,0.f}};

  for (int st = 0; st <= qt; ++st) {
    __syncthreads();
    // stage K tile (64x64) and V tile (32x64)
#pragma unroll
    for (int i = 0; i < 2; ++i) {
      int idx = tid + i * 256;
      int s = idx >> 3, g = idx & 7;
      bf16x8 v = *(const bf16x8*)(kbase + ((size_t)(st * 64 + s)) * DQK + g * 8);
      *(bf16x8*)(Klds + swz8(s, g)) = v;
    }
    {
      int dv = tid >> 3, g = tid & 7;
      bf16x8 v = *(const bf16x8*)(vbase + (size_t)dv * T_DIM + st * 64 + g * 8);
      *(bf16x8*)(Vlds + swz8(dv, g)) = v;
    }
    __syncthreads();

    // S^T[s][t]: 4 s row-tiles x (K=64 -> 2 mfma)
    f32x4 sacc[4];
#pragma unroll
    for (int rt = 0; rt < 4; ++rt) {
      f32x4 a = {0.f, 0.f, 0.f, 0.f};
      bf16x8 kf0 = *(const bf16x8*)(Klds + swz8(rt * 16 + lrow, lg));
      a = __builtin_amdgcn_mfma_f32_16x16x32_bf16(kf0, qf0, a, 0, 0, 0);
      bf16x8 kf1 = *(const bf16x8*)(Klds + swz8(rt * 16 + lrow, 4 + lg));
      a = __builtin_amdgcn_mfma_f32_16x16x32_bf16(kf1, qf1, a, 0, 0, 0);
      sacc[rt] = a;
    }

    // scale + causal mask (diag tile only): s_local = rt*16+4*lg+r, t_local = w*16+lrow
    float p[16];
    const bool diag = (st == qt);
    const int tl = w * 16 + lrow;
#pragma unroll
    for (int rt = 0; rt < 4; ++rt)
#pragma unroll
      for (int r = 0; r < 4; ++r) {
        float v = sacc[rt][r] * 0.125f;
        if (diag && (rt * 16 + lg * 4 + r) > tl) v = -INFINITY;
        p[rt * 4 + r] = v;
      }

    // online softmax: t is lane-local; reduce 16 lane values + groups via xor 16/32
    float pmax = p[0];
#pragma unroll
    for (int i = 1; i < 16; ++i) pmax = fmaxf(pmax, p[i]);
    pmax = fmaxf(pmax, __shfl_xor(pmax, 16));
    pmax = fmaxf(pmax, __shfl_xor(pmax, 32));
    const float mn = fmaxf(m, pmax);
    const float corr = __expf(m - mn);
    float ps = 0.f;
#pragma unroll
    for (int i = 0; i < 16; ++i) { p[i] = __expf(p[i] - mn); ps += p[i]; }
    ps += __shfl_xor(ps, 16);
    ps += __shfl_xor(ps, 32);
    l = l * corr + ps;
    m = mn;
#pragma unroll
    for (int dt = 0; dt < 2; ++dt) oacc[dt] = oacc[dt] * corr;

    // P -> LDS [16 t][64 s] (swizzled), row = lrow (own t)
#pragma unroll
    for (int rt = 0; rt < 4; ++rt)
#pragma unroll
      for (int r = 0; r < 4; ++r) {
        int s = rt * 16 + lg * 4 + r;
        int byte = lrow * 128 + ((((s >> 3) ^ (lrow & 7))) << 4) + ((s & 7) << 1);
        *(bf16*)(pw + byte) = (bf16)p[rt * 4 + r];
      }

    // O^T += Vt * P^T : 2 dv row-tiles x 2 k-steps
#pragma unroll
    for (int ks = 0; ks < 2; ++ks) {
      bf16x8 pf = *(const bf16x8*)(pw + swz8(lrow, ks * 4 + lg));
#pragma unroll
      for (int dt = 0; dt < 2; ++dt) {
        bf16x8 vf = *(const bf16x8*)(Vlds + swz8(dt * 16 + lrow, ks * 4 + lg));
        oacc[dt] = __builtin_amdgcn_mfma_f32_16x16x32_bf16(vf, pf, oacc[dt], 0, 0, 0);
      }
    }
  }

  // epilogue: dv rows = dt*16 + 4*lg + r (consecutive r), t = tg
  const float inv = 1.0f / l;
  const int n = nh >> 3, h = nh & 7;
#pragma unroll
  for (int dt = 0; dt < 2; ++dt) {
    const int dv0 = dt * 16 + lg * 4;
    bf16x4 pk;
#pragma unroll
    for (int r = 0; r < 4; ++r) pk[r] = (bf16)(oacc[dt][r] * inv);
    *(bf16x4*)(attT + ((size_t)n * T_DIM + tg) * C_DIM + h * DV + dv0) = pk;
  }
}

// ---------------- kernel 3: output projection ----------------
// C[t][o] = sum_c attT[n][t][c] * Wo[o][c] + bo[o]; fp32 out[n][o][t] packed stores.
__global__ __launch_bounds__(256) void k_proj(const bf16* __restrict__ attT,
    const float* __restrict__ Wo, const float* __restrict__ bo, float* __restrict__ out) {
  __shared__ __attribute__((aligned(16))) unsigned char lds[8192];
  const int tid = threadIdx.x;
  const int n = blockIdx.z;
  const int o0 = blockIdx.x * 64;
  const int tt = blockIdx.y * 64;
  const int w = tid >> 6, lane = tid & 63;
  const int lrow = lane & 15, lg = lane >> 4;

  const int srow = tid >> 2;
  const int sg = tid & 3;
  const bf16* arow = attT + ((size_t)n * T_DIM + tt + srow) * C_DIM;
  const float* brow = Wo + (size_t)(o0 + srow) * C_DIM;

  f32x4 acc[4] = {{0.f,0.f,0.f,0.f},{0.f,0.f,0.f,0.f},{0.f,0.f,0.f,0.f},{0.f,0.f,0.f,0.f}};
#pragma unroll 1
  for (int kk = 0; kk < 8; ++kk) {
    bf16x8 av = *(const bf16x8*)(arow + kk * 32 + sg * 8);
    *(bf16x8*)(lds + swz4(srow, sg)) = av;
    const float* bp = brow + kk * 32 + sg * 8;
    float4 b01 = *(const float4*)bp;
    float4 b23 = *(const float4*)(bp + 4);
    bf16x8 bv;
    bv[0] = (bf16)b01.x; bv[1] = (bf16)b01.y; bv[2] = (bf16)b01.z; bv[3] = (bf16)b01.w;
    bv[4] = (bf16)b23.x; bv[5] = (bf16)b23.y; bv[6] = (bf16)b23.z; bv[7] = (bf16)b23.w;
    *(bf16x8*)(lds + 4096 + swz4(srow, sg)) = bv;
    __syncthreads();
    bf16x8 af = *(const bf16x8*)(lds + swz4(w * 16 + lrow, lg));
#pragma unroll
    for (int ct = 0; ct < 4; ++ct) {
      bf16x8 bfv = *(const bf16x8*)(lds + 4096 + swz4(ct * 16 + lrow, lg));
      acc[ct] = __builtin_amdgcn_mfma_f32_16x16x32_bf16(af, bfv, acc[ct], 0, 0, 0);
    }
    __syncthreads();
  }

  // epilogue: t rows = tt + 16w + 4*lg + r (consecutive), o col = o0 + 16ct + lrow
  const int t0 = tt + w * 16 + lg * 4;
#pragma unroll
  for (int ct = 0; ct < 4; ++ct) {
    const int oo = o0 + ct * 16 + lrow;
    const float bb = bo[oo];
    f32x4 v = acc[ct];
    v[0] += bb; v[1] += bb; v[2] += bb; v[3] += bb;
    *(f32x4*)(out + ((size_t)n * C_DIM + oo) * T_DIM + t0) = v;
  }
}

extern "C" void kernel_launch(void* const* d_in, const int* in_sizes, int n_in,
                              void* d_out, int out_size, void* d_ws, size_t ws_size,
                              hipStream_t stream) {
  const float* x   = (const float*)d_in[0];
  const float* Wq  = (const float*)d_in[1];
  const float* bq  = (const float*)d_in[2];
  const float* Wkv = (const float*)d_in[3];
  const float* bkv = (const float*)d_in[4];
  const float* Wo  = (const float*)d_in[5];
  const float* bo  = (const float*)d_in[6];
  float* out = (float*)d_out;

  char* ws = (char*)d_ws;
  bf16* xT    = (bf16*)(ws);                       // 4 MB [8][1024][256]
  bf16* q_ws  = (bf16*)(ws + (4u << 20));          // 8 MB [8*8][1024][64]
  bf16* k_ws  = (bf16*)(ws + (12u << 20));         // 8 MB
  bf16* vT_ws = (bf16*)(ws + (20u << 20));         // 4 MB [8*8][32][1024]
  bf16* attT  = xT;                                // alias: xT dead after k_qkv

  k_transpose<<<dim3(16, 4, 8), 256, 0, stream>>>(x, xT);
  k_qkv<<<dim3(16, 20, 8), 256, 0, stream>>>(xT, Wq, bq, Wkv, bkv, q_ws, k_ws, vT_ws);
  k_attn<<<dim3(16, 64), 256, 0, stream>>>(q_ws, k_ws, vT_ws, attT);
  k_proj<<<dim3(4, 16, 8), 256, 0, stream>>>(attT, Wo, bo, out);
}

// Round 3
// 69.489 us; speedup vs baseline: 1.0810x; 1.0810x over previous
//
#include <hip/hip_runtime.h>
#include <hip/hip_bf16.h>
#include <math.h>

typedef __bf16 bf16;
typedef __attribute__((ext_vector_type(4))) __bf16 bf16x4;
typedef __attribute__((ext_vector_type(8))) __bf16 bf16x8;
typedef __attribute__((ext_vector_type(4))) float f32x4;

#define T_DIM 1024
#define C_DIM 256
#define HEADS 8

// All staged operands live in ws as pre-swizzled tile images: rows of 64 bf16
// (128B), XOR-swizzled on 16B granules so ds_read_b128 column-slices are
// conflict-free (G4). global_load_lds copies tiles linearly; the swizzle is
// baked into the global layout (m173: pre-swizzled source + linear LDS dest).
static __device__ __forceinline__ int tb(int row, int col) {
  return row * 128 + ((((col >> 3) ^ row) & 7) << 4) + ((col & 7) << 1);
}

// async 16B global->LDS; LDS dest is wave-uniform (offsets use tid>>6 only)
static __device__ __forceinline__ void gl16(const char* g, char* l) {
  __builtin_amdgcn_global_load_lds(
      (const __attribute__((address_space(1))) unsigned int*)g,
      (__attribute__((address_space(3))) unsigned int*)l, 16, 0, 0);
}
// stage one 16KB tile (128 rows x 64 cols bf16) with all 256 threads
static __device__ __forceinline__ void stage16k(const char* g, char* l, int tid) {
  const int w = (tid >> 6) * 1024, ln = (tid & 63) * 16;
#pragma unroll
  for (int i = 0; i < 4; ++i) gl16(g + i * 4096 + w + ln, l + i * 4096 + w);
}
static __device__ __forceinline__ void stage8k(const char* g, char* l, int tid) {
  const int w = (tid >> 6) * 1024, ln = (tid & 63) * 16;
#pragma unroll
  for (int i = 0; i < 2; ++i) gl16(g + i * 4096 + w + ln, l + i * 4096 + w);
}
static __device__ __forceinline__ void stage4k(const char* g, char* l, int tid) {
  gl16(g + (tid >> 6) * 1024 + (tid & 63) * 16, l + (tid >> 6) * 1024);
}

// ---------------- kernel 0: prep ----------------
// b<512: transpose x (n,256,1024) f32 -> xTt swizzled tiles [n][ntt 8][kk 4][128x64]
// b<532: [Wq;Wkv] f32 -> Wbt tiles [mt 10][kk 4][128x64]
// else : Wo f32 -> Wot tiles [mt 2][kk 4][128x64]
__global__ __launch_bounds__(256) void k_prep(const float* __restrict__ x,
    const float* __restrict__ Wq, const float* __restrict__ Wkv, const float* __restrict__ Wo,
    char* __restrict__ xTt, char* __restrict__ Wbt, char* __restrict__ Wot) {
  const int tid = threadIdx.x;
  const int b = blockIdx.x;
  if (b < 512) {
    __shared__ float tile[64][65];
    const int n = b >> 6, rem = b & 63, tt64 = rem >> 2, ct = (rem & 3) << 6;
    const float* xp = x + ((size_t)n * C_DIM + ct) * T_DIM + tt64 * 64;
    const int t = tid & 63, c0 = tid >> 6;
#pragma unroll
    for (int i = 0; i < 16; ++i) tile[c0 + i * 4][t] = xp[(size_t)(c0 + i * 4) * T_DIM + t];
    __syncthreads();
    char* dst = xTt + (((size_t)(n * 8 + (tt64 >> 1))) * 4 + (rem & 3)) * 16384;
    const int rbase = (tt64 & 1) * 64;
#pragma unroll
    for (int i = 0; i < 2; ++i) {
      const int idx = tid + i * 256;
      const int tl = idx >> 3, c8 = (idx & 7) * 8;
      bf16x8 v;
#pragma unroll
      for (int j = 0; j < 8; ++j) v[j] = (bf16)tile[c8 + j][tl];
      *(bf16x8*)(dst + tb(rbase + tl, c8)) = v;
    }
  } else {
    const bool isWo = (b >= 532);
    const int o0 = (b - (isWo ? 532 : 512)) * 64;
#pragma unroll
    for (int i = 0; i < 8; ++i) {
      const int idx = tid + i * 256;
      const int row = idx >> 5, c8 = (idx & 31) * 8;
      const int o = o0 + row;
      const float* src = isWo ? (Wo + (size_t)o * C_DIM + c8)
                              : (o < 512 ? Wq + (size_t)o * C_DIM + c8
                                         : Wkv + (size_t)(o - 512) * C_DIM + c8);
      float4 a = *(const float4*)src;
      float4 bq4 = *(const float4*)(src + 4);
      bf16x8 v;
      v[0]=(bf16)a.x; v[1]=(bf16)a.y; v[2]=(bf16)a.z; v[3]=(bf16)a.w;
      v[4]=(bf16)bq4.x; v[5]=(bf16)bq4.y; v[6]=(bf16)bq4.z; v[7]=(bf16)bq4.w;
      char* base = isWo ? Wot : Wbt;
      char* dst = base + (((size_t)(o >> 7)) * 4 + (c8 >> 6)) * 16384;
      *(bf16x8*)(dst + tb(o & 127, c8 & 63)) = v;
    }
  }
}

// ---------------- kernel 1: QKV projection (128x128 tile, BK=64) ----------------
// Single-buffer, 2-barrier m97 structure: stage(k) -> barrier -> MFMA -> barrier.
__global__ __launch_bounds__(256) void k_qkv(const char* __restrict__ Wbt, const char* __restrict__ xTt,
    const float* __restrict__ bq, const float* __restrict__ bkv,
    bf16* __restrict__ q_ws, char* __restrict__ Kt, char* __restrict__ Vt) {
  __shared__ __attribute__((aligned(128))) unsigned char smem[32768]; // A 16K | B 16K
  const int tid = threadIdx.x;
  const int nt = blockIdx.x, mt = blockIdx.y, n = blockIdx.z;
  const int w = tid >> 6, lane = tid & 63, lrow = lane & 15, lg = lane >> 4;
  const int wm = (w >> 1) * 64, wn = (w & 1) * 64;
  const char* gA = Wbt + (size_t)mt * 65536;
  const char* gB = xTt + ((size_t)(n * 8 + nt)) * 65536;

  f32x4 acc[4][4] = {};
#pragma unroll 1
  for (int kk = 0; kk < 4; ++kk) {
    stage16k(gA + kk * 16384, (char*)smem, tid);
    stage16k(gB + kk * 16384, (char*)smem + 16384, tid);
    __syncthreads();                       // drains vmcnt: tiles ready
    const char* As = (const char*)smem;
    const char* Bs = As + 16384;
    bf16x8 af[4][2], bv[4][2];
#pragma unroll
    for (int mi = 0; mi < 4; ++mi)
#pragma unroll
      for (int kh = 0; kh < 2; ++kh)
        af[mi][kh] = *(const bf16x8*)(As + tb(wm + mi * 16 + lrow, kh * 32 + lg * 8));
#pragma unroll
    for (int ni = 0; ni < 4; ++ni)
#pragma unroll
      for (int kh = 0; kh < 2; ++kh)
        bv[ni][kh] = *(const bf16x8*)(Bs + tb(wn + ni * 16 + lrow, kh * 32 + lg * 8));
#pragma unroll
    for (int kh = 0; kh < 2; ++kh)
#pragma unroll
      for (int mi = 0; mi < 4; ++mi)
#pragma unroll
        for (int ni = 0; ni < 4; ++ni)
          acc[mi][ni] = __builtin_amdgcn_mfma_f32_16x16x32_bf16(af[mi][kh], bv[ni][kh], acc[mi][ni], 0, 0, 0);
    __syncthreads();                       // reads done before next overwrite
  }

  // epilogue: o = mt*128 + wm + mi*16 + lg*4 + r ; t = nt*128 + wn + ni*16 + lrow
  const int obase = mt * 128 + wm + lg * 4;
  const int tcol0 = nt * 128 + wn + lrow;
#pragma unroll
  for (int mi = 0; mi < 4; ++mi) {
    const int o = obase + mi * 16;
    if (mt < 4) {                      // Q -> q_ws[nh][t][64] linear
      const float4 bb = *(const float4*)(bq + o);
      const int nh = n * 8 + (o >> 6), d = o & 63;
      bf16* qrow = q_ws + (size_t)nh * (T_DIM * 64) + d;
#pragma unroll
      for (int ni = 0; ni < 4; ++ni) {
        const int t = tcol0 + ni * 16;
        f32x4 v = acc[mi][ni];
        bf16x4 pk;
        pk[0]=(bf16)(v[0]+bb.x); pk[1]=(bf16)(v[1]+bb.y); pk[2]=(bf16)(v[2]+bb.z); pk[3]=(bf16)(v[3]+bb.w);
        *(bf16x4*)(qrow + (size_t)t * 64) = pk;
      }
    } else if (mt < 8) {               // K -> Kt swizzled tiles [nh][st][64x64]
      const int o2 = o - 512;
      const float4 bb = *(const float4*)(bkv + o2);
      const int nh = n * 8 + (o2 >> 6), d = o2 & 63;
      char* tbase = Kt + (size_t)nh * 16 * 8192;
#pragma unroll
      for (int ni = 0; ni < 4; ++ni) {
        const int t = tcol0 + ni * 16;
        f32x4 v = acc[mi][ni];
        bf16x4 pk;
        pk[0]=(bf16)(v[0]+bb.x); pk[1]=(bf16)(v[1]+bb.y); pk[2]=(bf16)(v[2]+bb.z); pk[3]=(bf16)(v[3]+bb.w);
        *(bf16x4*)(tbase + (t >> 6) * 8192 + tb(t & 63, d)) = pk;
      }
    } else {                           // V -> Vt swizzled tiles [nh][st][32x64]
      const int o3 = o - 1024;
      const float4 bb = *(const float4*)(bkv + 512 + o3);
      const float* bbp = (const float*)&bb;
      const int nh = n * 8 + (o3 >> 5), dv = o3 & 31;
      char* tbase = Vt + (size_t)nh * 16 * 4096;
#pragma unroll
      for (int ni = 0; ni < 4; ++ni) {
        const int t = tcol0 + ni * 16;
        f32x4 v = acc[mi][ni];
        char* tile = tbase + (t >> 6) * 4096;
#pragma unroll
        for (int r = 0; r < 4; ++r)
          *(bf16*)(tile + tb(dv + r, t & 63)) = (bf16)(v[r] + bbp[r]);
      }
    }
  }
}

// ---------------- kernel 2: causal attention (single-buffer, 2-barrier) ----------------
__global__ __launch_bounds__(256) void k_attn(const bf16* __restrict__ q_ws,
    const char* __restrict__ Kt, const char* __restrict__ Vt, char* __restrict__ attTt) {
  __shared__ __attribute__((aligned(128))) unsigned char smem[20480];
  // K: 0..8K ; V: 8K..12K ; P: 12K + w*2048
  const int tid = threadIdx.x;
  const int qt = blockIdx.x, nh = blockIdx.y;
  const int w = tid >> 6, lane = tid & 63, lrow = lane & 15, lg = lane >> 4;
  const int tg = qt * 64 + w * 16 + lrow;

  const bf16* qbase = q_ws + ((size_t)nh * T_DIM + tg) * 64;
  const bf16x8 qf0 = *(const bf16x8*)(qbase + lg * 8);
  const bf16x8 qf1 = *(const bf16x8*)(qbase + 32 + lg * 8);

  const char* Ktb = Kt + (size_t)nh * 16 * 8192;
  const char* Vtb = Vt + (size_t)nh * 16 * 4096;
  const char* Kb = (const char*)smem;
  const char* Vb = (const char*)smem + 8192;
  char* pw = (char*)smem + 12288 + w * 2048;

  float m = -INFINITY, l = 0.f;
  f32x4 oacc[2] = {};

  for (int st = 0; st <= qt; ++st) {
    stage8k(Ktb + st * 8192, (char*)smem, tid);
    stage4k(Vtb + st * 4096, (char*)smem + 8192, tid);
    __syncthreads();                 // drains vmcnt: K/V tile ready

    f32x4 sacc[4];
#pragma unroll
    for (int rt = 0; rt < 4; ++rt) {
      f32x4 a = {0.f, 0.f, 0.f, 0.f};
      bf16x8 kf0 = *(const bf16x8*)(Kb + tb(rt * 16 + lrow, lg * 8));
      a = __builtin_amdgcn_mfma_f32_16x16x32_bf16(kf0, qf0, a, 0, 0, 0);
      bf16x8 kf1 = *(const bf16x8*)(Kb + tb(rt * 16 + lrow, 32 + lg * 8));
      a = __builtin_amdgcn_mfma_f32_16x16x32_bf16(kf1, qf1, a, 0, 0, 0);
      sacc[rt] = a;
    }

    float p[16];
    const bool diag = (st == qt);
    const int tl = w * 16 + lrow;
#pragma unroll
    for (int rt = 0; rt < 4; ++rt)
#pragma unroll
      for (int r = 0; r < 4; ++r) {
        float v = sacc[rt][r] * 0.125f;
        if (diag && (rt * 16 + lg * 4 + r) > tl) v = -INFINITY;
        p[rt * 4 + r] = v;
      }

    float pmax = p[0];
#pragma unroll
    for (int i = 1; i < 16; ++i) pmax = fmaxf(pmax, p[i]);
    pmax = fmaxf(pmax, __shfl_xor(pmax, 16));
    pmax = fmaxf(pmax, __shfl_xor(pmax, 32));
    const float mn = fmaxf(m, pmax);
    const float corr = __expf(m - mn);
    float ps = 0.f;
#pragma unroll
    for (int i = 0; i < 16; ++i) { p[i] = __expf(p[i] - mn); ps += p[i]; }
    ps += __shfl_xor(ps, 16);
    ps += __shfl_xor(ps, 32);
    l = l * corr + ps;
    m = mn;
    oacc[0] = oacc[0] * corr;
    oacc[1] = oacc[1] * corr;

    // P -> per-wave LDS [16 t][64 s], packed bf16x4 (cols s consecutive)
#pragma unroll
    for (int rt = 0; rt < 4; ++rt) {
      bf16x4 pk;
#pragma unroll
      for (int r = 0; r < 4; ++r) pk[r] = (bf16)p[rt * 4 + r];
      *(bf16x4*)(pw + tb(lrow, rt * 16 + lg * 4)) = pk;
    }

#pragma unroll
    for (int ks = 0; ks < 2; ++ks) {
      bf16x8 pf = *(const bf16x8*)(pw + tb(lrow, ks * 32 + lg * 8));
#pragma unroll
      for (int dt = 0; dt < 2; ++dt) {
        bf16x8 vf = *(const bf16x8*)(Vb + tb(dt * 16 + lrow, ks * 32 + lg * 8));
        oacc[dt] = __builtin_amdgcn_mfma_f32_16x16x32_bf16(vf, pf, oacc[dt], 0, 0, 0);
      }
    }
    __syncthreads();                 // K/V reads done before next stage overwrite
  }

  // epilogue -> attTt swizzled tiles [n][ntt][kk][128x64]; rows=t, cols=h*32+dv
  const float inv = 1.0f / l;
  const int n = nh >> 3, h = nh & 7;
  const int ntt = tg >> 7, row = tg & 127;
#pragma unroll
  for (int dt = 0; dt < 2; ++dt) {
    const int c = h * 32 + dt * 16 + lg * 4;
    char* tile = attTt + (((size_t)(n * 8 + ntt)) * 4 + (c >> 6)) * 16384;
    bf16x4 pk;
#pragma unroll
    for (int r = 0; r < 4; ++r) pk[r] = (bf16)(oacc[dt][r] * inv);
    *(bf16x4*)(tile + tb(row, c & 63)) = pk;
  }
}

// ---------------- kernel 3: output projection (128x128 tile, BK=64) ----------------
// C[t][o] = attT[n][t][:] . Wo[o][:] + bo[o]; out[n][o][t] f32, f32x4 stores along t.
__global__ __launch_bounds__(256) void k_proj(const char* __restrict__ attTt,
    const char* __restrict__ Wot, const float* __restrict__ bo, float* __restrict__ out) {
  __shared__ __attribute__((aligned(128))) unsigned char smem[32768];
  const int tid = threadIdx.x;
  const int tm = blockIdx.x, om = blockIdx.y, n = blockIdx.z;
  const int w = tid >> 6, lane = tid & 63, lrow = lane & 15, lg = lane >> 4;
  const int wm = (w >> 1) * 64, wn = (w & 1) * 64;
  const char* gA = attTt + ((size_t)(n * 8 + tm)) * 65536;
  const char* gB = Wot + (size_t)om * 65536;

  f32x4 acc[4][4] = {};
#pragma unroll 1
  for (int kk = 0; kk < 4; ++kk) {
    stage16k(gA + kk * 16384, (char*)smem, tid);
    stage16k(gB + kk * 16384, (char*)smem + 16384, tid);
    __syncthreads();
    const char* As = (const char*)smem;
    const char* Bs = As + 16384;
    bf16x8 af[4][2], bv[4][2];
#pragma unroll
    for (int mi = 0; mi < 4; ++mi)
#pragma unroll
      for (int kh = 0; kh < 2; ++kh)
        af[mi][kh] = *(const bf16x8*)(As + tb(wm + mi * 16 + lrow, kh * 32 + lg * 8));
#pragma unroll
    for (int ni = 0; ni < 4; ++ni)
#pragma unroll
      for (int kh = 0; kh < 2; ++kh)
        bv[ni][kh] = *(const bf16x8*)(Bs + tb(wn + ni * 16 + lrow, kh * 32 + lg * 8));
#pragma unroll
    for (int kh = 0; kh < 2; ++kh)
#pragma unroll
      for (int mi = 0; mi < 4; ++mi)
#pragma unroll
        for (int ni = 0; ni < 4; ++ni)
          acc[mi][ni] = __builtin_amdgcn_mfma_f32_16x16x32_bf16(af[mi][kh], bv[ni][kh], acc[mi][ni], 0, 0, 0);
    __syncthreads();
  }

  // epilogue: t = tm*128 + wm + mi*16 + lg*4 + r ; o = om*128 + wn + ni*16 + lrow
  const int t0b = tm * 128 + wm + lg * 4;
  const int ob = om * 128 + wn + lrow;
#pragma unroll
  for (int mi = 0; mi < 4; ++mi) {
    const int t0 = t0b + mi * 16;
#pragma unroll
    for (int ni = 0; ni < 4; ++ni) {
      const int o = ob + ni * 16;
      const float bb = bo[o];
      f32x4 v = acc[mi][ni];
      v[0] += bb; v[1] += bb; v[2] += bb; v[3] += bb;
      *(f32x4*)(out + ((size_t)(n * C_DIM + o)) * T_DIM + t0) = v;
    }
  }
}

extern "C" void kernel_launch(void* const* d_in, const int* in_sizes, int n_in,
                              void* d_out, int out_size, void* d_ws, size_t ws_size,
                              hipStream_t stream) {
  const float* x   = (const float*)d_in[0];
  const float* Wq  = (const float*)d_in[1];
  const float* bq  = (const float*)d_in[2];
  const float* Wkv = (const float*)d_in[3];
  const float* bkv = (const float*)d_in[4];
  const float* Wo  = (const float*)d_in[5];
  const float* bo  = (const float*)d_in[6];
  float* out = (float*)d_out;

  char* ws = (char*)d_ws;
  char* xTt   = ws;                      // 4 MB   [8][8][4][16KB]
  char* Wbt   = ws + (4u  << 20);        // 640 KB [10][4][16KB]
  char* Wot   = ws + (5u  << 20);        // 128 KB [2][4][16KB]
  bf16* q_ws  = (bf16*)(ws + (6u << 20)); // 8 MB  [64][1024][64]
  char* Kt    = ws + (14u << 20);        // 8 MB   [64][16][8KB]
  char* Vt    = ws + (22u << 20);        // 4 MB   [64][16][4KB]
  char* attTt = ws + (26u << 20);        // 4 MB   [8][8][4][16KB]

  k_prep<<<536, 256, 0, stream>>>(x, Wq, Wkv, Wo, xTt, Wbt, Wot);
  k_qkv<<<dim3(8, 10, 8), 256, 0, stream>>>(Wbt, xTt, bq, bkv, q_ws, Kt, Vt);
  k_attn<<<dim3(16, 64), 256, 0, stream>>>(q_ws, Kt, Vt, attTt);
  k_proj<<<dim3(8, 2, 8), 256, 0, stream>>>(attTt, Wot, bo, out);
}

// Round 4
// 60.589 us; speedup vs baseline: 1.2398x; 1.1469x over previous
//
#include <hip/hip_runtime.h>
#include <hip/hip_bf16.h>
#include <math.h>

typedef __bf16 bf16;
typedef __attribute__((ext_vector_type(4))) __bf16 bf16x4;
typedef __attribute__((ext_vector_type(8))) __bf16 bf16x8;
typedef __attribute__((ext_vector_type(4))) float f32x4;

#define T_DIM 1024
#define C_DIM 256
#define HEADS 8

// All staged operands live in ws as pre-swizzled tile images: rows of 64 bf16
// (128B), XOR-swizzled on 16B granules so ds_read_b128 column-slices are
// conflict-free (G4). global_load_lds copies tiles linearly; the swizzle is
// baked into the global layout (m173: pre-swizzled source + linear LDS dest).
static __device__ __forceinline__ int tb(int row, int col) {
  return row * 128 + ((((col >> 3) ^ row) & 7) << 4) + ((col & 7) << 1);
}

// async 16B global->LDS; LDS dest is wave-uniform (offsets use tid>>6 only)
static __device__ __forceinline__ void gl16(const char* g, char* l) {
  __builtin_amdgcn_global_load_lds(
      (const __attribute__((address_space(1))) unsigned int*)g,
      (__attribute__((address_space(3))) unsigned int*)l, 16, 0, 0);
}
// stage one 16KB tile (128 rows x 64 cols bf16) with all 256 threads
static __device__ __forceinline__ void stage16k(const char* g, char* l, int tid) {
  const int w = (tid >> 6) * 1024, ln = (tid & 63) * 16;
#pragma unroll
  for (int i = 0; i < 4; ++i) gl16(g + i * 4096 + w + ln, l + i * 4096 + w);
}
static __device__ __forceinline__ void stage8k(const char* g, char* l, int tid) {
  const int w = (tid >> 6) * 1024, ln = (tid & 63) * 16;
#pragma unroll
  for (int i = 0; i < 2; ++i) gl16(g + i * 4096 + w + ln, l + i * 4096 + w);
}
static __device__ __forceinline__ void stage4k(const char* g, char* l, int tid) {
  gl16(g + (tid >> 6) * 1024 + (tid & 63) * 16, l + (tid >> 6) * 1024);
}

// ---------------- kernel 0: prep ----------------
// b<512: transpose x (n,256,1024) f32 -> xTt swizzled tiles [n][ntt 8][kk 4][128x64]
// b<532: [Wq;Wkv] f32 -> Wbt tiles [mt 10][kk 4][128x64]
// else : Wo f32 -> Wot tiles [mt 2][kk 4][128x64]
__global__ __launch_bounds__(256) void k_prep(const float* __restrict__ x,
    const float* __restrict__ Wq, const float* __restrict__ Wkv, const float* __restrict__ Wo,
    char* __restrict__ xTt, char* __restrict__ Wbt, char* __restrict__ Wot) {
  const int tid = threadIdx.x;
  const int b = blockIdx.x;
  if (b < 512) {
    __shared__ float tile[64][65];
    const int n = b >> 6, rem = b & 63, tt64 = rem >> 2, ct = (rem & 3) << 6;
    const float* xp = x + ((size_t)n * C_DIM + ct) * T_DIM + tt64 * 64;
    const int t = tid & 63, c0 = tid >> 6;
#pragma unroll
    for (int i = 0; i < 16; ++i) tile[c0 + i * 4][t] = xp[(size_t)(c0 + i * 4) * T_DIM + t];
    __syncthreads();
    char* dst = xTt + (((size_t)(n * 8 + (tt64 >> 1))) * 4 + (rem & 3)) * 16384;
    const int rbase = (tt64 & 1) * 64;
#pragma unroll
    for (int i = 0; i < 2; ++i) {
      const int idx = tid + i * 256;
      const int tl = idx >> 3, c8 = (idx & 7) * 8;
      bf16x8 v;
#pragma unroll
      for (int j = 0; j < 8; ++j) v[j] = (bf16)tile[c8 + j][tl];
      *(bf16x8*)(dst + tb(rbase + tl, c8)) = v;
    }
  } else {
    const bool isWo = (b >= 532);
    const int o0 = (b - (isWo ? 532 : 512)) * 64;
#pragma unroll
    for (int i = 0; i < 8; ++i) {
      const int idx = tid + i * 256;
      const int row = idx >> 5, c8 = (idx & 31) * 8;
      const int o = o0 + row;
      const float* src = isWo ? (Wo + (size_t)o * C_DIM + c8)
                              : (o < 512 ? Wq + (size_t)o * C_DIM + c8
                                         : Wkv + (size_t)(o - 512) * C_DIM + c8);
      float4 a = *(const float4*)src;
      float4 bq4 = *(const float4*)(src + 4);
      bf16x8 v;
      v[0]=(bf16)a.x; v[1]=(bf16)a.y; v[2]=(bf16)a.z; v[3]=(bf16)a.w;
      v[4]=(bf16)bq4.x; v[5]=(bf16)bq4.y; v[6]=(bf16)bq4.z; v[7]=(bf16)bq4.w;
      char* base = isWo ? Wot : Wbt;
      char* dst = base + (((size_t)(o >> 7)) * 4 + (c8 >> 6)) * 16384;
      *(bf16x8*)(dst + tb(o & 127, c8 & 63)) = v;
    }
  }
}

// ---------------- kernel 1: QKV projection (128x128 tile, BK=64) ----------------
// Single-buffer, 2-barrier m97 structure: stage(k) -> barrier -> MFMA -> barrier.
__global__ __launch_bounds__(256) void k_qkv(const char* __restrict__ Wbt, const char* __restrict__ xTt,
    const float* __restrict__ bq, const float* __restrict__ bkv,
    bf16* __restrict__ q_ws, char* __restrict__ Kt, char* __restrict__ Vt) {
  __shared__ __attribute__((aligned(128))) unsigned char smem[32768]; // A 16K | B 16K
  const int tid = threadIdx.x;
  const int nt = blockIdx.x, mt = blockIdx.y, n = blockIdx.z;
  const int w = tid >> 6, lane = tid & 63, lrow = lane & 15, lg = lane >> 4;
  const int wm = (w >> 1) * 64, wn = (w & 1) * 64;
  const char* gA = Wbt + (size_t)mt * 65536;
  const char* gB = xTt + ((size_t)(n * 8 + nt)) * 65536;

  f32x4 acc[4][4] = {};
#pragma unroll 1
  for (int kk = 0; kk < 4; ++kk) {
    stage16k(gA + kk * 16384, (char*)smem, tid);
    stage16k(gB + kk * 16384, (char*)smem + 16384, tid);
    __syncthreads();                       // drains vmcnt: tiles ready
    const char* As = (const char*)smem;
    const char* Bs = As + 16384;
    bf16x8 af[4][2], bv[4][2];
#pragma unroll
    for (int mi = 0; mi < 4; ++mi)
#pragma unroll
      for (int kh = 0; kh < 2; ++kh)
        af[mi][kh] = *(const bf16x8*)(As + tb(wm + mi * 16 + lrow, kh * 32 + lg * 8));
#pragma unroll
    for (int ni = 0; ni < 4; ++ni)
#pragma unroll
      for (int kh = 0; kh < 2; ++kh)
        bv[ni][kh] = *(const bf16x8*)(Bs + tb(wn + ni * 16 + lrow, kh * 32 + lg * 8));
#pragma unroll
    for (int kh = 0; kh < 2; ++kh)
#pragma unroll
      for (int mi = 0; mi < 4; ++mi)
#pragma unroll
        for (int ni = 0; ni < 4; ++ni)
          acc[mi][ni] = __builtin_amdgcn_mfma_f32_16x16x32_bf16(af[mi][kh], bv[ni][kh], acc[mi][ni], 0, 0, 0);
    __syncthreads();                       // reads done before next overwrite
  }

  // epilogue: o = mt*128 + wm + mi*16 + lg*4 + r ; t = nt*128 + wn + ni*16 + lrow
  const int obase = mt * 128 + wm + lg * 4;
  const int tcol0 = nt * 128 + wn + lrow;
#pragma unroll
  for (int mi = 0; mi < 4; ++mi) {
    const int o = obase + mi * 16;
    if (mt < 4) {                      // Q -> q_ws[nh][t][64] linear
      const float4 bb = *(const float4*)(bq + o);
      const int nh = n * 8 + (o >> 6), d = o & 63;
      bf16* qrow = q_ws + (size_t)nh * (T_DIM * 64) + d;
#pragma unroll
      for (int ni = 0; ni < 4; ++ni) {
        const int t = tcol0 + ni * 16;
        f32x4 v = acc[mi][ni];
        bf16x4 pk;
        pk[0]=(bf16)(v[0]+bb.x); pk[1]=(bf16)(v[1]+bb.y); pk[2]=(bf16)(v[2]+bb.z); pk[3]=(bf16)(v[3]+bb.w);
        *(bf16x4*)(qrow + (size_t)t * 64) = pk;
      }
    } else if (mt < 8) {               // K -> Kt swizzled tiles [nh][st][64x64]
      const int o2 = o - 512;
      const float4 bb = *(const float4*)(bkv + o2);
      const int nh = n * 8 + (o2 >> 6), d = o2 & 63;
      char* tbase = Kt + (size_t)nh * 16 * 8192;
#pragma unroll
      for (int ni = 0; ni < 4; ++ni) {
        const int t = tcol0 + ni * 16;
        f32x4 v = acc[mi][ni];
        bf16x4 pk;
        pk[0]=(bf16)(v[0]+bb.x); pk[1]=(bf16)(v[1]+bb.y); pk[2]=(bf16)(v[2]+bb.z); pk[3]=(bf16)(v[3]+bb.w);
        *(bf16x4*)(tbase + (t >> 6) * 8192 + tb(t & 63, d)) = pk;
      }
    } else {                           // V -> Vt swizzled tiles [nh][st][32x64]
      const int o3 = o - 1024;
      const float4 bb = *(const float4*)(bkv + 512 + o3);
      const float* bbp = (const float*)&bb;
      const int nh = n * 8 + (o3 >> 5), dv = o3 & 31;
      char* tbase = Vt + (size_t)nh * 16 * 4096;
#pragma unroll
      for (int ni = 0; ni < 4; ++ni) {
        const int t = tcol0 + ni * 16;
        f32x4 v = acc[mi][ni];
        char* tile = tbase + (t >> 6) * 4096;
#pragma unroll
        for (int r = 0; r < 4; ++r)
          *(bf16*)(tile + tb(dv + r, t & 63)) = (bf16)(v[r] + bbp[r]);
      }
    }
  }
}

// ---------------- kernel 2: causal attention ----------------
// Block (nh, qp): processes qt=qp then qt=15-qp -> exactly 17 steps/block
// (uniform work regardless of dispatch policy). 512 blocks, 2/CU.
// Inner step body = proven round-3 structure (stage -> bar -> compute -> bar),
// softmax in exp2 domain (logit scale folds in log2(e)).
__global__ __launch_bounds__(256) void k_attn(const bf16* __restrict__ q_ws,
    const char* __restrict__ Kt, const char* __restrict__ Vt, char* __restrict__ attTt) {
  __shared__ __attribute__((aligned(128))) unsigned char smem[20480];
  // K: 0..8K ; V: 8K..12K ; P: 12K + w*2048
  const int tid = threadIdx.x;
  const int nh = blockIdx.x, qp = blockIdx.y;
  const int w = tid >> 6, lane = tid & 63, lrow = lane & 15, lg = lane >> 4;

  const char* Ktb = Kt + (size_t)nh * 16 * 8192;
  const char* Vtb = Vt + (size_t)nh * 16 * 4096;
  const char* Kb = (const char*)smem;
  const char* Vb = (const char*)smem + 8192;
  char* pw = (char*)smem + 12288 + w * 2048;
  const int n = nh >> 3, h = nh & 7;
  const float s2 = 0.18033688f;   // 0.125 * log2(e)

#pragma unroll 1
  for (int ph = 0; ph < 2; ++ph) {
    const int qt = ph ? (15 - qp) : qp;
    const int tg = qt * 64 + w * 16 + lrow;
    const bf16* qbase = q_ws + ((size_t)nh * T_DIM + tg) * 64;
    const bf16x8 qf0 = *(const bf16x8*)(qbase + lg * 8);
    const bf16x8 qf1 = *(const bf16x8*)(qbase + 32 + lg * 8);

    float m = -INFINITY, l = 0.f;
    f32x4 oacc[2] = {};

    for (int st = 0; st <= qt; ++st) {
      stage8k(Ktb + st * 8192, (char*)smem, tid);
      stage4k(Vtb + st * 4096, (char*)smem + 8192, tid);
      __syncthreads();                 // drains vmcnt: K/V tile ready

      f32x4 sacc[4];
#pragma unroll
      for (int rt = 0; rt < 4; ++rt) {
        f32x4 a = {0.f, 0.f, 0.f, 0.f};
        bf16x8 kf0 = *(const bf16x8*)(Kb + tb(rt * 16 + lrow, lg * 8));
        a = __builtin_amdgcn_mfma_f32_16x16x32_bf16(kf0, qf0, a, 0, 0, 0);
        bf16x8 kf1 = *(const bf16x8*)(Kb + tb(rt * 16 + lrow, 32 + lg * 8));
        a = __builtin_amdgcn_mfma_f32_16x16x32_bf16(kf1, qf1, a, 0, 0, 0);
        sacc[rt] = a;
      }

      float p[16];
      const bool diag = (st == qt);
      const int tl = w * 16 + lrow;
#pragma unroll
      for (int rt = 0; rt < 4; ++rt)
#pragma unroll
        for (int r = 0; r < 4; ++r) {
          float v = sacc[rt][r] * s2;   // log2 domain
          if (diag && (rt * 16 + lg * 4 + r) > tl) v = -INFINITY;
          p[rt * 4 + r] = v;
        }

      float pmax = p[0];
#pragma unroll
      for (int i = 1; i < 16; ++i) pmax = fmaxf(pmax, p[i]);
      pmax = fmaxf(pmax, __shfl_xor(pmax, 16));
      pmax = fmaxf(pmax, __shfl_xor(pmax, 32));
      const float mn = fmaxf(m, pmax);
      const float corr = exp2f(m - mn);
      float ps = 0.f;
#pragma unroll
      for (int i = 0; i < 16; ++i) { p[i] = exp2f(p[i] - mn); ps += p[i]; }
      ps += __shfl_xor(ps, 16);
      ps += __shfl_xor(ps, 32);
      l = l * corr + ps;
      m = mn;
      oacc[0] = oacc[0] * corr;
      oacc[1] = oacc[1] * corr;

      // P -> per-wave LDS [16 t][64 s], packed bf16x4 (cols s consecutive)
#pragma unroll
      for (int rt = 0; rt < 4; ++rt) {
        bf16x4 pk;
#pragma unroll
        for (int r = 0; r < 4; ++r) pk[r] = (bf16)p[rt * 4 + r];
        *(bf16x4*)(pw + tb(lrow, rt * 16 + lg * 4)) = pk;
      }

#pragma unroll
      for (int ks = 0; ks < 2; ++ks) {
        bf16x8 pf = *(const bf16x8*)(pw + tb(lrow, ks * 32 + lg * 8));
#pragma unroll
        for (int dt = 0; dt < 2; ++dt) {
          bf16x8 vf = *(const bf16x8*)(Vb + tb(dt * 16 + lrow, ks * 32 + lg * 8));
          oacc[dt] = __builtin_amdgcn_mfma_f32_16x16x32_bf16(vf, pf, oacc[dt], 0, 0, 0);
        }
      }
      __syncthreads();                 // K/V reads done before next stage overwrite
    }

    // epilogue -> attTt swizzled tiles [n][ntt][kk][128x64]; rows=t, cols=h*32+dv
    const float inv = 1.0f / l;
    const int ntt = tg >> 7, row = tg & 127;
#pragma unroll
    for (int dt = 0; dt < 2; ++dt) {
      const int c = h * 32 + dt * 16 + lg * 4;
      char* tile = attTt + (((size_t)(n * 8 + ntt)) * 4 + (c >> 6)) * 16384;
      bf16x4 pk;
#pragma unroll
      for (int r = 0; r < 4; ++r) pk[r] = (bf16)(oacc[dt][r] * inv);
      *(bf16x4*)(tile + tb(row, c & 63)) = pk;
    }
  }
}

// ---------------- kernel 3: output projection (128t x 64o tile, BK=64) ----------------
// C[t][o] = attT[n][t][:] . Wo[o][:] + bo[o]; out[n][o][t] f32, f32x4 stores along t.
// 256 blocks (was 128) for occupancy on this tiny latency-bound GEMM.
__global__ __launch_bounds__(256) void k_proj(const char* __restrict__ attTt,
    const char* __restrict__ Wot, const float* __restrict__ bo, float* __restrict__ out) {
  __shared__ __attribute__((aligned(128))) unsigned char smem[24576]; // A 16K | B 8K
  const int tid = threadIdx.x;
  const int tm = blockIdx.x, om = blockIdx.y, n = blockIdx.z;
  const int w = tid >> 6, lane = tid & 63, lrow = lane & 15, lg = lane >> 4;
  const int wm = (w >> 1) * 64, wn = (w & 1) * 32;
  const char* gA = attTt + ((size_t)(n * 8 + tm)) * 65536;
  const char* gB = Wot + (size_t)(om >> 1) * 65536 + (om & 1) * 8192; // 64-row half-tile

  f32x4 acc[4][2] = {};
#pragma unroll 1
  for (int kk = 0; kk < 4; ++kk) {
    stage16k(gA + kk * 16384, (char*)smem, tid);
    stage8k(gB + kk * 16384, (char*)smem + 16384, tid);
    __syncthreads();
    const char* As = (const char*)smem;
    const char* Bs = As + 16384;
    bf16x8 af[4][2], bv[2][2];
#pragma unroll
    for (int mi = 0; mi < 4; ++mi)
#pragma unroll
      for (int kh = 0; kh < 2; ++kh)
        af[mi][kh] = *(const bf16x8*)(As + tb(wm + mi * 16 + lrow, kh * 32 + lg * 8));
#pragma unroll
    for (int ni = 0; ni < 2; ++ni)
#pragma unroll
      for (int kh = 0; kh < 2; ++kh)
        bv[ni][kh] = *(const bf16x8*)(Bs + tb(wn + ni * 16 + lrow, kh * 32 + lg * 8));
#pragma unroll
    for (int kh = 0; kh < 2; ++kh)
#pragma unroll
      for (int mi = 0; mi < 4; ++mi)
#pragma unroll
        for (int ni = 0; ni < 2; ++ni)
          acc[mi][ni] = __builtin_amdgcn_mfma_f32_16x16x32_bf16(af[mi][kh], bv[ni][kh], acc[mi][ni], 0, 0, 0);
    __syncthreads();
  }

  // epilogue: t = tm*128 + wm + mi*16 + lg*4 + r ; o = om*64 + wn + ni*16 + lrow
  const int t0b = tm * 128 + wm + lg * 4;
  const int ob = om * 64 + wn + lrow;
#pragma unroll
  for (int mi = 0; mi < 4; ++mi) {
    const int t0 = t0b + mi * 16;
#pragma unroll
    for (int ni = 0; ni < 2; ++ni) {
      const int o = ob + ni * 16;
      const float bb = bo[o];
      f32x4 v = acc[mi][ni];
      v[0] += bb; v[1] += bb; v[2] += bb; v[3] += bb;
      *(f32x4*)(out + ((size_t)(n * C_DIM + o)) * T_DIM + t0) = v;
    }
  }
}

extern "C" void kernel_launch(void* const* d_in, const int* in_sizes, int n_in,
                              void* d_out, int out_size, void* d_ws, size_t ws_size,
                              hipStream_t stream) {
  const float* x   = (const float*)d_in[0];
  const float* Wq  = (const float*)d_in[1];
  const float* bq  = (const float*)d_in[2];
  const float* Wkv = (const float*)d_in[3];
  const float* bkv = (const float*)d_in[4];
  const float* Wo  = (const float*)d_in[5];
  const float* bo  = (const float*)d_in[6];
  float* out = (float*)d_out;

  char* ws = (char*)d_ws;
  char* xTt   = ws;                      // 4 MB   [8][8][4][16KB]
  char* Wbt   = ws + (4u  << 20);        // 640 KB [10][4][16KB]
  char* Wot   = ws + (5u  << 20);        // 128 KB [2][4][16KB]
  bf16* q_ws  = (bf16*)(ws + (6u << 20)); // 8 MB  [64][1024][64]
  char* Kt    = ws + (14u << 20);        // 8 MB   [64][16][8KB]
  char* Vt    = ws + (22u << 20);        // 4 MB   [64][16][4KB]
  char* attTt = ws + (26u << 20);        // 4 MB   [8][8][4][16KB]

  k_prep<<<536, 256, 0, stream>>>(x, Wq, Wkv, Wo, xTt, Wbt, Wot);
  k_qkv<<<dim3(8, 10, 8), 256, 0, stream>>>(Wbt, xTt, bq, bkv, q_ws, Kt, Vt);
  k_attn<<<dim3(64, 8), 256, 0, stream>>>(q_ws, Kt, Vt, attTt);
  k_proj<<<dim3(8, 4, 8), 256, 0, stream>>>(attTt, Wot, bo, out);
}

// Round 5
// 59.989 us; speedup vs baseline: 1.2522x; 1.0100x over previous
//
#include <hip/hip_runtime.h>
#include <hip/hip_bf16.h>
#include <math.h>

typedef __bf16 bf16;
typedef __attribute__((ext_vector_type(4))) __bf16 bf16x4;
typedef __attribute__((ext_vector_type(8))) __bf16 bf16x8;
typedef __attribute__((ext_vector_type(4))) float f32x4;

#define T_DIM 1024
#define C_DIM 256
#define HEADS 8

// All staged operands live in ws as pre-swizzled tile images: rows of 64 bf16
// (128B), XOR-swizzled on 16B granules so ds_read_b128 column-slices are
// conflict-free (G4). global_load_lds copies tiles linearly; the swizzle is
// baked into the global layout (m173: pre-swizzled source + linear LDS dest).
static __device__ __forceinline__ int tb(int row, int col) {
  return row * 128 + ((((col >> 3) ^ row) & 7) << 4) + ((col & 7) << 1);
}

// async 16B global->LDS; LDS dest is wave-uniform (offsets use tid>>6 only)
static __device__ __forceinline__ void gl16(const char* g, char* l) {
  __builtin_amdgcn_global_load_lds(
      (const __attribute__((address_space(1))) unsigned int*)g,
      (__attribute__((address_space(3))) unsigned int*)l, 16, 0, 0);
}
// stage one 16KB tile (128 rows x 64 cols bf16) with all 256 threads
static __device__ __forceinline__ void stage16k(const char* g, char* l, int tid) {
  const int w = (tid >> 6) * 1024, ln = (tid & 63) * 16;
#pragma unroll
  for (int i = 0; i < 4; ++i) gl16(g + i * 4096 + w + ln, l + i * 4096 + w);
}
static __device__ __forceinline__ void stage8k(const char* g, char* l, int tid) {
  const int w = (tid >> 6) * 1024, ln = (tid & 63) * 16;
#pragma unroll
  for (int i = 0; i < 2; ++i) gl16(g + i * 4096 + w + ln, l + i * 4096 + w);
}
static __device__ __forceinline__ void stage4k(const char* g, char* l, int tid) {
  gl16(g + (tid >> 6) * 1024 + (tid & 63) * 16, l + (tid >> 6) * 1024);
}

// ---------------- kernel 0: prep ----------------
__global__ __launch_bounds__(256) void k_prep(const float* __restrict__ x,
    const float* __restrict__ Wq, const float* __restrict__ Wkv, const float* __restrict__ Wo,
    char* __restrict__ xTt, char* __restrict__ Wbt, char* __restrict__ Wot) {
  const int tid = threadIdx.x;
  const int b = blockIdx.x;
  if (b < 512) {
    __shared__ float tile[64][65];
    const int n = b >> 6, rem = b & 63, tt64 = rem >> 2, ct = (rem & 3) << 6;
    const float* xp = x + ((size_t)n * C_DIM + ct) * T_DIM + tt64 * 64;
    const int t = tid & 63, c0 = tid >> 6;
#pragma unroll
    for (int i = 0; i < 16; ++i) tile[c0 + i * 4][t] = xp[(size_t)(c0 + i * 4) * T_DIM + t];
    __syncthreads();
    char* dst = xTt + (((size_t)(n * 8 + (tt64 >> 1))) * 4 + (rem & 3)) * 16384;
    const int rbase = (tt64 & 1) * 64;
#pragma unroll
    for (int i = 0; i < 2; ++i) {
      const int idx = tid + i * 256;
      const int tl = idx >> 3, c8 = (idx & 7) * 8;
      bf16x8 v;
#pragma unroll
      for (int j = 0; j < 8; ++j) v[j] = (bf16)tile[c8 + j][tl];
      *(bf16x8*)(dst + tb(rbase + tl, c8)) = v;
    }
  } else {
    const bool isWo = (b >= 532);
    const int o0 = (b - (isWo ? 532 : 512)) * 64;
#pragma unroll
    for (int i = 0; i < 8; ++i) {
      const int idx = tid + i * 256;
      const int row = idx >> 5, c8 = (idx & 31) * 8;
      const int o = o0 + row;
      const float* src = isWo ? (Wo + (size_t)o * C_DIM + c8)
                              : (o < 512 ? Wq + (size_t)o * C_DIM + c8
                                         : Wkv + (size_t)(o - 512) * C_DIM + c8);
      float4 a = *(const float4*)src;
      float4 bq4 = *(const float4*)(src + 4);
      bf16x8 v;
      v[0]=(bf16)a.x; v[1]=(bf16)a.y; v[2]=(bf16)a.z; v[3]=(bf16)a.w;
      v[4]=(bf16)bq4.x; v[5]=(bf16)bq4.y; v[6]=(bf16)bq4.z; v[7]=(bf16)bq4.w;
      char* base = isWo ? Wot : Wbt;
      char* dst = base + (((size_t)(o >> 7)) * 4 + (c8 >> 6)) * 16384;
      *(bf16x8*)(dst + tb(o & 127, c8 & 63)) = v;
    }
  }
}

// ---------------- kernel 1: QKV projection (128x128 tile, BK=64) ----------------
// Single-buffer, 2-barrier m97 structure. V-epilogue: LDS transpose -> 16B stores.
__global__ __launch_bounds__(256) void k_qkv(const char* __restrict__ Wbt, const char* __restrict__ xTt,
    const float* __restrict__ bq, const float* __restrict__ bkv,
    bf16* __restrict__ q_ws, char* __restrict__ Kt, char* __restrict__ Vt) {
  __shared__ __attribute__((aligned(128))) unsigned char smem[34816]; // A 16K | B 16K ; V-transpose reuse
  const int tid = threadIdx.x;
  const int nt = blockIdx.x, mt = blockIdx.y, n = blockIdx.z;
  const int w = tid >> 6, lane = tid & 63, lrow = lane & 15, lg = lane >> 4;
  const int wm = (w >> 1) * 64, wn = (w & 1) * 64;
  const char* gA = Wbt + (size_t)mt * 65536;
  const char* gB = xTt + ((size_t)(n * 8 + nt)) * 65536;

  f32x4 acc[4][4] = {};
#pragma unroll 1
  for (int kk = 0; kk < 4; ++kk) {
    stage16k(gA + kk * 16384, (char*)smem, tid);
    stage16k(gB + kk * 16384, (char*)smem + 16384, tid);
    __syncthreads();                       // drains vmcnt: tiles ready
    const char* As = (const char*)smem;
    const char* Bs = As + 16384;
    bf16x8 af[4][2], bv[4][2];
#pragma unroll
    for (int mi = 0; mi < 4; ++mi)
#pragma unroll
      for (int kh = 0; kh < 2; ++kh)
        af[mi][kh] = *(const bf16x8*)(As + tb(wm + mi * 16 + lrow, kh * 32 + lg * 8));
#pragma unroll
    for (int ni = 0; ni < 4; ++ni)
#pragma unroll
      for (int kh = 0; kh < 2; ++kh)
        bv[ni][kh] = *(const bf16x8*)(Bs + tb(wn + ni * 16 + lrow, kh * 32 + lg * 8));
#pragma unroll
    for (int kh = 0; kh < 2; ++kh)
#pragma unroll
      for (int mi = 0; mi < 4; ++mi)
#pragma unroll
        for (int ni = 0; ni < 4; ++ni)
          acc[mi][ni] = __builtin_amdgcn_mfma_f32_16x16x32_bf16(af[mi][kh], bv[ni][kh], acc[mi][ni], 0, 0, 0);
    __syncthreads();                       // reads done before next overwrite / epilogue reuse
  }

  // epilogue: o = mt*128 + wm + mi*16 + lg*4 + r ; t = nt*128 + wn + ni*16 + lrow
  const int obase = mt * 128 + wm + lg * 4;
  const int tcol0 = nt * 128 + wn + lrow;
  if (mt < 8) {
#pragma unroll
    for (int mi = 0; mi < 4; ++mi) {
      const int o = obase + mi * 16;
      if (mt < 4) {                      // Q -> q_ws[nh][t][64] linear
        const float4 bb = *(const float4*)(bq + o);
        const int nh = n * 8 + (o >> 6), d = o & 63;
        bf16* qrow = q_ws + (size_t)nh * (T_DIM * 64) + d;
#pragma unroll
        for (int ni = 0; ni < 4; ++ni) {
          const int t = tcol0 + ni * 16;
          f32x4 v = acc[mi][ni];
          bf16x4 pk;
          pk[0]=(bf16)(v[0]+bb.x); pk[1]=(bf16)(v[1]+bb.y); pk[2]=(bf16)(v[2]+bb.z); pk[3]=(bf16)(v[3]+bb.w);
          *(bf16x4*)(qrow + (size_t)t * 64) = pk;
        }
      } else {                           // K -> Kt swizzled tiles [nh][st][64x64]
        const int o2 = o - 512;
        const float4 bb = *(const float4*)(bkv + o2);
        const int nh = n * 8 + (o2 >> 6), d = o2 & 63;
        char* tbase = Kt + (size_t)nh * 16 * 8192;
#pragma unroll
        for (int ni = 0; ni < 4; ++ni) {
          const int t = tcol0 + ni * 16;
          f32x4 v = acc[mi][ni];
          bf16x4 pk;
          pk[0]=(bf16)(v[0]+bb.x); pk[1]=(bf16)(v[1]+bb.y); pk[2]=(bf16)(v[2]+bb.z); pk[3]=(bf16)(v[3]+bb.w);
          *(bf16x4*)(tbase + (t >> 6) * 8192 + tb(t & 63, d)) = pk;
        }
      }
    }
  } else {
    // V route: acc -> LDS [o3l 128][132 bf16 row] (+bias), then 16B granule
    // stores into Vt swizzled tiles (fixes the 2B global scatter).
    bf16* tp = (bf16*)smem;              // stride 132 elems (264B, 8B-aligned rows)
#pragma unroll
    for (int mi = 0; mi < 4; ++mi) {
      const int o3g = (mt - 8) * 128 + wm + mi * 16 + lg * 4;
      const float4 bb = *(const float4*)(bkv + 512 + o3g);
      const float* bbp = (const float*)&bb;
      const int o3l = wm + mi * 16 + lg * 4;
#pragma unroll
      for (int ni = 0; ni < 4; ++ni) {
        const int tl = wn + ni * 16 + lrow;
        f32x4 v = acc[mi][ni];
#pragma unroll
        for (int r = 0; r < 4; ++r)
          tp[(o3l + r) * 132 + tl] = (bf16)(v[r] + bbp[r]);
      }
    }
    __syncthreads();
    const int row = tid >> 1, half = tid & 1;   // 128 rows x 2 t-halves
    const int o3 = (mt - 8) * 128 + row;
    const int nh = n * 8 + (o3 >> 5), dv = o3 & 31;
    char* tile = Vt + (size_t)nh * 16 * 4096 + (nt * 2 + half) * 4096;
    const bf16* src = tp + row * 132 + half * 64;
#pragma unroll
    for (int g = 0; g < 8; ++g) {
      bf16x4 lo = *(const bf16x4*)(src + g * 8);
      bf16x4 hi = *(const bf16x4*)(src + g * 8 + 4);
      bf16x8 vv;
      vv[0]=lo[0]; vv[1]=lo[1]; vv[2]=lo[2]; vv[3]=lo[3];
      vv[4]=hi[0]; vv[5]=hi[1]; vv[6]=hi[2]; vv[7]=hi[3];
      *(bf16x8*)(tile + tb(dv, g * 8)) = vv;
    }
  }
}

// ---------------- kernel 2: causal attention (128-key steps) ----------------
// Block (nh, qp): qt = qp then 15-qp -> 9 steps/block uniform.
// Per step: stage 2x(K 8K) + 2x(V 4K) sub-tiles -> barrier -> S for both,
// joint softmax over 32 logits, PV per sub-tile (separate P regions) -> barrier.
__global__ __launch_bounds__(256) void k_attn(const bf16* __restrict__ q_ws,
    const char* __restrict__ Kt, const char* __restrict__ Vt, char* __restrict__ attTt) {
  __shared__ __attribute__((aligned(128))) unsigned char smem[40960];
  // K: 0 / 8192 ; V: 16384 / 20480 ; P: 24576 + w*4096 + sub*2048
  const int tid = threadIdx.x;
  const int nh = blockIdx.x, qp = blockIdx.y;
  const int w = tid >> 6, lane = tid & 63, lrow = lane & 15, lg = lane >> 4;

  const char* Ktb = Kt + (size_t)nh * 16 * 8192;
  const char* Vtb = Vt + (size_t)nh * 16 * 4096;
  char* Kb[2] = { (char*)smem, (char*)smem + 8192 };
  char* Vb[2] = { (char*)smem + 16384, (char*)smem + 20480 };
  char* pw[2] = { (char*)smem + 24576 + w * 4096, (char*)smem + 24576 + w * 4096 + 2048 };
  const int n = nh >> 3, h = nh & 7;
  const float s2 = 0.18033688f;   // 0.125 * log2(e)
  const int tl = w * 16 + lrow;

#pragma unroll 1
  for (int ph = 0; ph < 2; ++ph) {
    const int qt = ph ? (15 - qp) : qp;
    const int tg = qt * 64 + tl;
    const bf16* qbase = q_ws + ((size_t)nh * T_DIM + tg) * 64;
    const bf16x8 qf0 = *(const bf16x8*)(qbase + lg * 8);
    const bf16x8 qf1 = *(const bf16x8*)(qbase + 32 + lg * 8);

    float m = -INFINITY, l = 0.f;
    f32x4 oacc[2] = {};

    int st2 = 0;
#pragma unroll 1
    for (; st2 + 1 <= qt; st2 += 2) {        // full 128-key steps
      stage8k(Ktb + (size_t)st2 * 8192, Kb[0], tid);
      stage8k(Ktb + (size_t)(st2 + 1) * 8192, Kb[1], tid);
      stage4k(Vtb + (size_t)st2 * 4096, Vb[0], tid);
      stage4k(Vtb + (size_t)(st2 + 1) * 4096, Vb[1], tid);
      __syncthreads();                       // drains vmcnt: sub-tiles ready

      f32x4 sacc[2][4];
#pragma unroll
      for (int sub = 0; sub < 2; ++sub)
#pragma unroll
        for (int rt = 0; rt < 4; ++rt) {
          f32x4 a = {0.f, 0.f, 0.f, 0.f};
          bf16x8 kf0 = *(const bf16x8*)(Kb[sub] + tb(rt * 16 + lrow, lg * 8));
          a = __builtin_amdgcn_mfma_f32_16x16x32_bf16(kf0, qf0, a, 0, 0, 0);
          bf16x8 kf1 = *(const bf16x8*)(Kb[sub] + tb(rt * 16 + lrow, 32 + lg * 8));
          a = __builtin_amdgcn_mfma_f32_16x16x32_bf16(kf1, qf1, a, 0, 0, 0);
          sacc[sub][rt] = a;
        }

      const bool diag1 = (st2 + 1 == qt);
      float p[2][16];
#pragma unroll
      for (int sub = 0; sub < 2; ++sub)
#pragma unroll
        for (int rt = 0; rt < 4; ++rt)
#pragma unroll
          for (int r = 0; r < 4; ++r) {
            float v = sacc[sub][rt][r] * s2;   // log2 domain
            if (sub == 1 && diag1 && (rt * 16 + lg * 4 + r) > tl) v = -INFINITY;
            p[sub][rt * 4 + r] = v;
          }

      float pmax = p[0][0];
#pragma unroll
      for (int i = 1; i < 16; ++i) pmax = fmaxf(pmax, p[0][i]);
#pragma unroll
      for (int i = 0; i < 16; ++i) pmax = fmaxf(pmax, p[1][i]);
      pmax = fmaxf(pmax, __shfl_xor(pmax, 16));
      pmax = fmaxf(pmax, __shfl_xor(pmax, 32));
      const float mn = fmaxf(m, pmax);
      const float corr = exp2f(m - mn);
      float ps = 0.f;
#pragma unroll
      for (int sub = 0; sub < 2; ++sub)
#pragma unroll
        for (int i = 0; i < 16; ++i) { p[sub][i] = exp2f(p[sub][i] - mn); ps += p[sub][i]; }
      ps += __shfl_xor(ps, 16);
      ps += __shfl_xor(ps, 32);
      l = l * corr + ps;
      m = mn;
      oacc[0] = oacc[0] * corr;
      oacc[1] = oacc[1] * corr;

#pragma unroll
      for (int sub = 0; sub < 2; ++sub) {
#pragma unroll
        for (int rt = 0; rt < 4; ++rt) {
          bf16x4 pk;
#pragma unroll
          for (int r = 0; r < 4; ++r) pk[r] = (bf16)p[sub][rt * 4 + r];
          *(bf16x4*)(pw[sub] + tb(lrow, rt * 16 + lg * 4)) = pk;
        }
#pragma unroll
        for (int ks = 0; ks < 2; ++ks) {
          bf16x8 pf = *(const bf16x8*)(pw[sub] + tb(lrow, ks * 32 + lg * 8));
#pragma unroll
          for (int dt = 0; dt < 2; ++dt) {
            bf16x8 vf = *(const bf16x8*)(Vb[sub] + tb(dt * 16 + lrow, ks * 32 + lg * 8));
            oacc[dt] = __builtin_amdgcn_mfma_f32_16x16x32_bf16(vf, pf, oacc[dt], 0, 0, 0);
          }
        }
      }
      __syncthreads();                 // reads done before next stage overwrite
    }

    if (st2 <= qt) {                   // single 64-key tail (qt even) — always diag
      stage8k(Ktb + (size_t)st2 * 8192, Kb[0], tid);
      stage4k(Vtb + (size_t)st2 * 4096, Vb[0], tid);
      __syncthreads();

      f32x4 sacc[4];
#pragma unroll
      for (int rt = 0; rt < 4; ++rt) {
        f32x4 a = {0.f, 0.f, 0.f, 0.f};
        bf16x8 kf0 = *(const bf16x8*)(Kb[0] + tb(rt * 16 + lrow, lg * 8));
        a = __builtin_amdgcn_mfma_f32_16x16x32_bf16(kf0, qf0, a, 0, 0, 0);
        bf16x8 kf1 = *(const bf16x8*)(Kb[0] + tb(rt * 16 + lrow, 32 + lg * 8));
        a = __builtin_amdgcn_mfma_f32_16x16x32_bf16(kf1, qf1, a, 0, 0, 0);
        sacc[rt] = a;
      }

      float p[16];
#pragma unroll
      for (int rt = 0; rt < 4; ++rt)
#pragma unroll
        for (int r = 0; r < 4; ++r) {
          float v = sacc[rt][r] * s2;
          if ((rt * 16 + lg * 4 + r) > tl) v = -INFINITY;
          p[rt * 4 + r] = v;
        }

      float pmax = p[0];
#pragma unroll
      for (int i = 1; i < 16; ++i) pmax = fmaxf(pmax, p[i]);
      pmax = fmaxf(pmax, __shfl_xor(pmax, 16));
      pmax = fmaxf(pmax, __shfl_xor(pmax, 32));
      const float mn = fmaxf(m, pmax);
      const float corr = exp2f(m - mn);
      float ps = 0.f;
#pragma unroll
      for (int i = 0; i < 16; ++i) { p[i] = exp2f(p[i] - mn); ps += p[i]; }
      ps += __shfl_xor(ps, 16);
      ps += __shfl_xor(ps, 32);
      l = l * corr + ps;
      m = mn;
      oacc[0] = oacc[0] * corr;
      oacc[1] = oacc[1] * corr;

#pragma unroll
      for (int rt = 0; rt < 4; ++rt) {
        bf16x4 pk;
#pragma unroll
        for (int r = 0; r < 4; ++r) pk[r] = (bf16)p[rt * 4 + r];
        *(bf16x4*)(pw[0] + tb(lrow, rt * 16 + lg * 4)) = pk;
      }
#pragma unroll
      for (int ks = 0; ks < 2; ++ks) {
        bf16x8 pf = *(const bf16x8*)(pw[0] + tb(lrow, ks * 32 + lg * 8));
#pragma unroll
        for (int dt = 0; dt < 2; ++dt) {
          bf16x8 vf = *(const bf16x8*)(Vb[0] + tb(dt * 16 + lrow, ks * 32 + lg * 8));
          oacc[dt] = __builtin_amdgcn_mfma_f32_16x16x32_bf16(vf, pf, oacc[dt], 0, 0, 0);
        }
      }
      __syncthreads();
    }

    // epilogue -> attTt swizzled tiles [n][ntt][kk][128x64]; rows=t, cols=h*32+dv
    const float inv = 1.0f / l;
    const int ntt = tg >> 7, row = tg & 127;
#pragma unroll
    for (int dt = 0; dt < 2; ++dt) {
      const int c = h * 32 + dt * 16 + lg * 4;
      char* tile = attTt + (((size_t)(n * 8 + ntt)) * 4 + (c >> 6)) * 16384;
      bf16x4 pk;
#pragma unroll
      for (int r = 0; r < 4; ++r) pk[r] = (bf16)(oacc[dt][r] * inv);
      *(bf16x4*)(tile + tb(row, c & 63)) = pk;
    }
  }
}

// ---------------- kernel 3: output projection (128t x 64o tile, BK=64) ----------------
__global__ __launch_bounds__(256) void k_proj(const char* __restrict__ attTt,
    const char* __restrict__ Wot, const float* __restrict__ bo, float* __restrict__ out) {
  __shared__ __attribute__((aligned(128))) unsigned char smem[24576]; // A 16K | B 8K
  const int tid = threadIdx.x;
  const int tm = blockIdx.x, om = blockIdx.y, n = blockIdx.z;
  const int w = tid >> 6, lane = tid & 63, lrow = lane & 15, lg = lane >> 4;
  const int wm = (w >> 1) * 64, wn = (w & 1) * 32;
  const char* gA = attTt + ((size_t)(n * 8 + tm)) * 65536;
  const char* gB = Wot + (size_t)(om >> 1) * 65536 + (om & 1) * 8192; // 64-row half-tile

  f32x4 acc[4][2] = {};
#pragma unroll 1
  for (int kk = 0; kk < 4; ++kk) {
    stage16k(gA + kk * 16384, (char*)smem, tid);
    stage8k(gB + kk * 16384, (char*)smem + 16384, tid);
    __syncthreads();
    const char* As = (const char*)smem;
    const char* Bs = As + 16384;
    bf16x8 af[4][2], bv[2][2];
#pragma unroll
    for (int mi = 0; mi < 4; ++mi)
#pragma unroll
      for (int kh = 0; kh < 2; ++kh)
        af[mi][kh] = *(const bf16x8*)(As + tb(wm + mi * 16 + lrow, kh * 32 + lg * 8));
#pragma unroll
    for (int ni = 0; ni < 2; ++ni)
#pragma unroll
      for (int kh = 0; kh < 2; ++kh)
        bv[ni][kh] = *(const bf16x8*)(Bs + tb(wn + ni * 16 + lrow, kh * 32 + lg * 8));
#pragma unroll
    for (int kh = 0; kh < 2; ++kh)
#pragma unroll
      for (int mi = 0; mi < 4; ++mi)
#pragma unroll
        for (int ni = 0; ni < 2; ++ni)
          acc[mi][ni] = __builtin_amdgcn_mfma_f32_16x16x32_bf16(af[mi][kh], bv[ni][kh], acc[mi][ni], 0, 0, 0);
    __syncthreads();
  }

  // epilogue: t = tm*128 + wm + mi*16 + lg*4 + r ; o = om*64 + wn + ni*16 + lrow
  const int t0b = tm * 128 + wm + lg * 4;
  const int ob = om * 64 + wn + lrow;
#pragma unroll
  for (int mi = 0; mi < 4; ++mi) {
    const int t0 = t0b + mi * 16;
#pragma unroll
    for (int ni = 0; ni < 2; ++ni) {
      const int o = ob + ni * 16;
      const float bb = bo[o];
      f32x4 v = acc[mi][ni];
      v[0] += bb; v[1] += bb; v[2] += bb; v[3] += bb;
      *(f32x4*)(out + ((size_t)(n * C_DIM + o)) * T_DIM + t0) = v;
    }
  }
}

extern "C" void kernel_launch(void* const* d_in, const int* in_sizes, int n_in,
                              void* d_out, int out_size, void* d_ws, size_t ws_size,
                              hipStream_t stream) {
  const float* x   = (const float*)d_in[0];
  const float* Wq  = (const float*)d_in[1];
  const float* bq  = (const float*)d_in[2];
  const float* Wkv = (const float*)d_in[3];
  const float* bkv = (const float*)d_in[4];
  const float* Wo  = (const float*)d_in[5];
  const float* bo  = (const float*)d_in[6];
  float* out = (float*)d_out;

  char* ws = (char*)d_ws;
  char* xTt   = ws;                      // 4 MB   [8][8][4][16KB]
  char* Wbt   = ws + (4u  << 20);        // 640 KB [10][4][16KB]
  char* Wot   = ws + (5u  << 20);        // 128 KB [2][4][16KB]
  bf16* q_ws  = (bf16*)(ws + (6u << 20)); // 8 MB  [64][1024][64]
  char* Kt    = ws + (14u << 20);        // 8 MB   [64][16][8KB]
  char* Vt    = ws + (22u << 20);        // 4 MB   [64][16][4KB]
  char* attTt = ws + (26u << 20);        // 4 MB   [8][8][4][16KB]

  k_prep<<<536, 256, 0, stream>>>(x, Wq, Wkv, Wo, xTt, Wbt, Wot);
  k_qkv<<<dim3(8, 10, 8), 256, 0, stream>>>(Wbt, xTt, bq, bkv, q_ws, Kt, Vt);
  k_attn<<<dim3(64, 8), 256, 0, stream>>>(q_ws, Kt, Vt, attTt);
  k_proj<<<dim3(8, 4, 8), 256, 0, stream>>>(attTt, Wot, bo, out);
}

// Round 6
// 59.576 us; speedup vs baseline: 1.2609x; 1.0069x over previous
//
#include <hip/hip_runtime.h>
#include <hip/hip_bf16.h>
#include <math.h>

typedef __bf16 bf16;
typedef __attribute__((ext_vector_type(4))) __bf16 bf16x4;
typedef __attribute__((ext_vector_type(8))) __bf16 bf16x8;
typedef __attribute__((ext_vector_type(4))) float f32x4;

#define T_DIM 1024
#define C_DIM 256
#define HEADS 8

// Pre-swizzled tile images: rows of 64 bf16 (128B), XOR-swizzled on 16B
// granules so ds_read_b128 column-slices are conflict-free (G4). Staged via
// linear global_load_lds (m173: swizzle baked into the global layout).
static __device__ __forceinline__ int tb(int row, int col) {
  return row * 128 + ((((col >> 3) ^ row) & 7) << 4) + ((col & 7) << 1);
}

static __device__ __forceinline__ void gl16(const char* g, char* l) {
  __builtin_amdgcn_global_load_lds(
      (const __attribute__((address_space(1))) unsigned int*)g,
      (__attribute__((address_space(3))) unsigned int*)l, 16, 0, 0);
}
static __device__ __forceinline__ void stage16k(const char* g, char* l, int tid) {
  const int w = (tid >> 6) * 1024, ln = (tid & 63) * 16;
#pragma unroll
  for (int i = 0; i < 4; ++i) gl16(g + i * 4096 + w + ln, l + i * 4096 + w);
}
static __device__ __forceinline__ void stage8k(const char* g, char* l, int tid) {
  const int w = (tid >> 6) * 1024, ln = (tid & 63) * 16;
#pragma unroll
  for (int i = 0; i < 2; ++i) gl16(g + i * 4096 + w + ln, l + i * 4096 + w);
}
static __device__ __forceinline__ void stage4k(const char* g, char* l, int tid) {
  gl16(g + (tid >> 6) * 1024 + (tid & 63) * 16, l + (tid >> 6) * 1024);
}

// ---------------- kernel 0: prep ----------------
__global__ __launch_bounds__(256) void k_prep(const float* __restrict__ x,
    const float* __restrict__ Wq, const float* __restrict__ Wkv, const float* __restrict__ Wo,
    char* __restrict__ xTt, char* __restrict__ Wbt, char* __restrict__ Wot) {
  const int tid = threadIdx.x;
  const int b = blockIdx.x;
  if (b < 512) {
    __shared__ float tile[64][65];
    const int n = b >> 6, rem = b & 63, tt64 = rem >> 2, ct = (rem & 3) << 6;
    const float* xp = x + ((size_t)n * C_DIM + ct) * T_DIM + tt64 * 64;
    const int t4 = (tid & 15) * 4, c0 = tid >> 4;
#pragma unroll
    for (int i = 0; i < 4; ++i) {
      const int c = c0 + i * 16;
      float4 v = *(const float4*)(xp + (size_t)c * T_DIM + t4);
      tile[c][t4] = v.x; tile[c][t4 + 1] = v.y; tile[c][t4 + 2] = v.z; tile[c][t4 + 3] = v.w;
    }
    __syncthreads();
    char* dst = xTt + (((size_t)(n * 8 + (tt64 >> 1))) * 4 + (rem & 3)) * 16384;
    const int rbase = (tt64 & 1) * 64;
#pragma unroll
    for (int i = 0; i < 2; ++i) {
      const int idx = tid + i * 256;
      const int tl = idx >> 3, c8 = (idx & 7) * 8;
      bf16x8 v;
#pragma unroll
      for (int j = 0; j < 8; ++j) v[j] = (bf16)tile[c8 + j][tl];
      *(bf16x8*)(dst + tb(rbase + tl, c8)) = v;
    }
  } else {
    const bool isWo = (b >= 532);
    const int o0 = (b - (isWo ? 532 : 512)) * 64;
#pragma unroll
    for (int i = 0; i < 8; ++i) {
      const int idx = tid + i * 256;
      const int row = idx >> 5, c8 = (idx & 31) * 8;
      const int o = o0 + row;
      const float* src = isWo ? (Wo + (size_t)o * C_DIM + c8)
                              : (o < 512 ? Wq + (size_t)o * C_DIM + c8
                                         : Wkv + (size_t)(o - 512) * C_DIM + c8);
      float4 a = *(const float4*)src;
      float4 bq4 = *(const float4*)(src + 4);
      bf16x8 v;
      v[0]=(bf16)a.x; v[1]=(bf16)a.y; v[2]=(bf16)a.z; v[3]=(bf16)a.w;
      v[4]=(bf16)bq4.x; v[5]=(bf16)bq4.y; v[6]=(bf16)bq4.z; v[7]=(bf16)bq4.w;
      char* base = isWo ? Wot : Wbt;
      char* dst = base + (((size_t)(o >> 7)) * 4 + (c8 >> 6)) * 16384;
      *(bf16x8*)(dst + tb(o & 127, c8 & 63)) = v;
    }
  }
}

// ---------------- kernel 1: QKV projection (128x128 tile, BK=64) ----------------
// Single-buffer, 2-barrier m97 structure. V-epilogue: LDS transpose -> 16B stores.
__global__ __launch_bounds__(256) void k_qkv(const char* __restrict__ Wbt, const char* __restrict__ xTt,
    const float* __restrict__ bq, const float* __restrict__ bkv,
    bf16* __restrict__ q_ws, char* __restrict__ Kt, char* __restrict__ Vt) {
  __shared__ __attribute__((aligned(128))) unsigned char smem[34816];
  const int tid = threadIdx.x;
  const int nt = blockIdx.x, mt = blockIdx.y, n = blockIdx.z;
  const int w = tid >> 6, lane = tid & 63, lrow = lane & 15, lg = lane >> 4;
  const int wm = (w >> 1) * 64, wn = (w & 1) * 64;
  const char* gA = Wbt + (size_t)mt * 65536;
  const char* gB = xTt + ((size_t)(n * 8 + nt)) * 65536;

  f32x4 acc[4][4] = {};
#pragma unroll 1
  for (int kk = 0; kk < 4; ++kk) {
    stage16k(gA + kk * 16384, (char*)smem, tid);
    stage16k(gB + kk * 16384, (char*)smem + 16384, tid);
    __syncthreads();
    const char* As = (const char*)smem;
    const char* Bs = As + 16384;
    bf16x8 af[4][2], bv[4][2];
#pragma unroll
    for (int mi = 0; mi < 4; ++mi)
#pragma unroll
      for (int kh = 0; kh < 2; ++kh)
        af[mi][kh] = *(const bf16x8*)(As + tb(wm + mi * 16 + lrow, kh * 32 + lg * 8));
#pragma unroll
    for (int ni = 0; ni < 4; ++ni)
#pragma unroll
      for (int kh = 0; kh < 2; ++kh)
        bv[ni][kh] = *(const bf16x8*)(Bs + tb(wn + ni * 16 + lrow, kh * 32 + lg * 8));
#pragma unroll
    for (int kh = 0; kh < 2; ++kh)
#pragma unroll
      for (int mi = 0; mi < 4; ++mi)
#pragma unroll
        for (int ni = 0; ni < 4; ++ni)
          acc[mi][ni] = __builtin_amdgcn_mfma_f32_16x16x32_bf16(af[mi][kh], bv[ni][kh], acc[mi][ni], 0, 0, 0);
    __syncthreads();
  }

  const int obase = mt * 128 + wm + lg * 4;
  const int tcol0 = nt * 128 + wn + lrow;
  if (mt < 8) {
#pragma unroll
    for (int mi = 0; mi < 4; ++mi) {
      const int o = obase + mi * 16;
      if (mt < 4) {                      // Q -> q_ws[nh][t][64] linear
        const float4 bb = *(const float4*)(bq + o);
        const int nh = n * 8 + (o >> 6), d = o & 63;
        bf16* qrow = q_ws + (size_t)nh * (T_DIM * 64) + d;
#pragma unroll
        for (int ni = 0; ni < 4; ++ni) {
          const int t = tcol0 + ni * 16;
          f32x4 v = acc[mi][ni];
          bf16x4 pk;
          pk[0]=(bf16)(v[0]+bb.x); pk[1]=(bf16)(v[1]+bb.y); pk[2]=(bf16)(v[2]+bb.z); pk[3]=(bf16)(v[3]+bb.w);
          *(bf16x4*)(qrow + (size_t)t * 64) = pk;
        }
      } else {                           // K -> Kt swizzled tiles [nh][st][64x64]
        const int o2 = o - 512;
        const float4 bb = *(const float4*)(bkv + o2);
        const int nh = n * 8 + (o2 >> 6), d = o2 & 63;
        char* tbase = Kt + (size_t)nh * 16 * 8192;
#pragma unroll
        for (int ni = 0; ni < 4; ++ni) {
          const int t = tcol0 + ni * 16;
          f32x4 v = acc[mi][ni];
          bf16x4 pk;
          pk[0]=(bf16)(v[0]+bb.x); pk[1]=(bf16)(v[1]+bb.y); pk[2]=(bf16)(v[2]+bb.z); pk[3]=(bf16)(v[3]+bb.w);
          *(bf16x4*)(tbase + (t >> 6) * 8192 + tb(t & 63, d)) = pk;
        }
      }
    }
  } else {
    // V route: acc -> LDS [128][132] (+bias), then 16B granule stores into Vt.
    bf16* tp = (bf16*)smem;
#pragma unroll
    for (int mi = 0; mi < 4; ++mi) {
      const int o3g = (mt - 8) * 128 + wm + mi * 16 + lg * 4;
      const float4 bb = *(const float4*)(bkv + 512 + o3g);
      const float* bbp = (const float*)&bb;
      const int o3l = wm + mi * 16 + lg * 4;
#pragma unroll
      for (int ni = 0; ni < 4; ++ni) {
        const int tl = wn + ni * 16 + lrow;
        f32x4 v = acc[mi][ni];
#pragma unroll
        for (int r = 0; r < 4; ++r)
          tp[(o3l + r) * 132 + tl] = (bf16)(v[r] + bbp[r]);
      }
    }
    __syncthreads();
    const int row = tid >> 1, half = tid & 1;
    const int o3 = (mt - 8) * 128 + row;
    const int nh = n * 8 + (o3 >> 5), dv = o3 & 31;
    char* tile = Vt + (size_t)nh * 16 * 4096 + (nt * 2 + half) * 4096;
    const bf16* src = tp + row * 132 + half * 64;
#pragma unroll
    for (int g = 0; g < 8; ++g) {
      bf16x4 lo = *(const bf16x4*)(src + g * 8);
      bf16x4 hi = *(const bf16x4*)(src + g * 8 + 4);
      bf16x8 vv;
      vv[0]=lo[0]; vv[1]=lo[1]; vv[2]=lo[2]; vv[3]=lo[3];
      vv[4]=hi[0]; vv[5]=hi[1]; vv[6]=hi[2]; vv[7]=hi[3];
      *(bf16x8*)(tile + tb(dv, g * 8)) = vv;
    }
  }
}

// ---------------- kernel 2: causal attention (single K-sweep, 2 Q-tiles) ----------------
// Block (nh,qp) owns Q-tiles qt0=qp and qt1=15-qp; ONE sweep over key tiles
// st=0..qt1 updates both online-softmax states -> 16-qp staged tiles (was 17),
// constant 17 tile-computes. Proven stage->bar->compute->bar topology.
__global__ __launch_bounds__(256) void k_attn(const bf16* __restrict__ q_ws,
    const char* __restrict__ Kt, const char* __restrict__ Vt, char* __restrict__ attTt) {
  __shared__ __attribute__((aligned(128))) unsigned char smem[40960];
  // K: 0 / 8192 ; V: 16384 / 20480 ; P: 24576 + w*4096 + sub*2048
  const int tid = threadIdx.x;
  const int nh = blockIdx.x, qp = blockIdx.y;
  const int w = tid >> 6, lane = tid & 63, lrow = lane & 15, lg = lane >> 4;
  const int tl = w * 16 + lrow;
  const char* Ktb = Kt + (size_t)nh * 16 * 8192;
  const char* Vtb = Vt + (size_t)nh * 16 * 4096;
  const int n = nh >> 3, h = nh & 7;
  const float s2 = 0.18033688f;   // 0.125 * log2(e)

  const int qt0 = qp, qt1 = 15 - qp;   // qt0 <= 7 < 8 <= qt1 (never equal)
  const int tg0 = qt0 * 64 + tl, tg1 = qt1 * 64 + tl;
  const bf16* qb0 = q_ws + ((size_t)nh * T_DIM + tg0) * 64;
  const bf16* qb1 = q_ws + ((size_t)nh * T_DIM + tg1) * 64;
  const bf16x8 qA0 = *(const bf16x8*)(qb0 + lg * 8);
  const bf16x8 qA1 = *(const bf16x8*)(qb0 + 32 + lg * 8);
  const bf16x8 qB0 = *(const bf16x8*)(qb1 + lg * 8);
  const bf16x8 qB1 = *(const bf16x8*)(qb1 + 32 + lg * 8);

  float m0 = -INFINITY, l0 = 0.f, m1 = -INFINITY, l1 = 0.f;
  f32x4 o0a = {}, o0b = {}, o1a = {}, o1b = {};

  // one flash update for one Q-state against the staged sub-tile
  auto proc = [&](bf16x8 qf0, bf16x8 qf1, float& m, float& l, f32x4& oa, f32x4& ob,
                  const char* Kbs, const char* Vbs, char* pws, bool diag) {
    f32x4 sacc[4];
    __builtin_amdgcn_s_setprio(1);
#pragma unroll
    for (int rt = 0; rt < 4; ++rt) {
      f32x4 a = {0.f, 0.f, 0.f, 0.f};
      bf16x8 kf0 = *(const bf16x8*)(Kbs + tb(rt * 16 + lrow, lg * 8));
      a = __builtin_amdgcn_mfma_f32_16x16x32_bf16(kf0, qf0, a, 0, 0, 0);
      bf16x8 kf1 = *(const bf16x8*)(Kbs + tb(rt * 16 + lrow, 32 + lg * 8));
      a = __builtin_amdgcn_mfma_f32_16x16x32_bf16(kf1, qf1, a, 0, 0, 0);
      sacc[rt] = a;
    }
    __builtin_amdgcn_s_setprio(0);
    float p[16];
#pragma unroll
    for (int rt = 0; rt < 4; ++rt)
#pragma unroll
      for (int r = 0; r < 4; ++r) {
        float v = sacc[rt][r] * s2;
        if (diag && (rt * 16 + lg * 4 + r) > tl) v = -INFINITY;
        p[rt * 4 + r] = v;
      }
    float pmax = p[0];
#pragma unroll
    for (int i = 1; i < 16; ++i) pmax = fmaxf(pmax, p[i]);
    pmax = fmaxf(pmax, __shfl_xor(pmax, 16));
    pmax = fmaxf(pmax, __shfl_xor(pmax, 32));
    const float mn = fmaxf(m, pmax);
    const float corr = exp2f(m - mn);
    float ps = 0.f;
#pragma unroll
    for (int i = 0; i < 16; ++i) { p[i] = exp2f(p[i] - mn); ps += p[i]; }
    ps += __shfl_xor(ps, 16);
    ps += __shfl_xor(ps, 32);
    l = l * corr + ps;
    m = mn;
    oa = oa * corr;
    ob = ob * corr;
#pragma unroll
    for (int rt = 0; rt < 4; ++rt) {
      bf16x4 pk;
#pragma unroll
      for (int r = 0; r < 4; ++r) pk[r] = (bf16)p[rt * 4 + r];
      *(bf16x4*)(pws + tb(lrow, rt * 16 + lg * 4)) = pk;
    }
    __builtin_amdgcn_s_setprio(1);
#pragma unroll
    for (int ks = 0; ks < 2; ++ks) {
      bf16x8 pf = *(const bf16x8*)(pws + tb(lrow, ks * 32 + lg * 8));
      bf16x8 vf0 = *(const bf16x8*)(Vbs + tb(lrow, ks * 32 + lg * 8));
      oa = __builtin_amdgcn_mfma_f32_16x16x32_bf16(vf0, pf, oa, 0, 0, 0);
      bf16x8 vf1 = *(const bf16x8*)(Vbs + tb(16 + lrow, ks * 32 + lg * 8));
      ob = __builtin_amdgcn_mfma_f32_16x16x32_bf16(vf1, pf, ob, 0, 0, 0);
    }
    __builtin_amdgcn_s_setprio(0);
  };

#pragma unroll 1
  for (int st2 = 0; st2 <= qt1; st2 += 2) {
    const bool has1 = (st2 + 1 <= qt1);
    stage8k(Ktb + (size_t)st2 * 8192, (char*)smem, tid);
    if (has1) stage8k(Ktb + (size_t)(st2 + 1) * 8192, (char*)smem + 8192, tid);
    stage4k(Vtb + (size_t)st2 * 4096, (char*)smem + 16384, tid);
    if (has1) stage4k(Vtb + (size_t)(st2 + 1) * 4096, (char*)smem + 20480, tid);
    __syncthreads();                     // drains vmcnt: sub-tiles ready
    const int nsub = has1 ? 2 : 1;
#pragma unroll 1
    for (int sub = 0; sub < nsub; ++sub) {
      const int stk = st2 + sub;
      const char* Kbs = (const char*)smem + sub * 8192;
      const char* Vbs = (const char*)smem + 16384 + sub * 4096;
      char* pws = (char*)smem + 24576 + w * 4096 + sub * 2048;
      proc(qB0, qB1, m1, l1, o1a, o1b, Kbs, Vbs, pws, stk == qt1);
      if (stk <= qt0)
        proc(qA0, qA1, m0, l0, o0a, o0b, Kbs, Vbs, pws, stk == qt0);
    }
    __syncthreads();                     // reads done before next stage overwrite
  }

  // epilogue -> attTt swizzled tiles [n][ntt][kk][128x64]; rows=t, cols=h*32+dv
  auto epi = [&](int tg, float l, f32x4 oa, f32x4 ob) {
    const float inv = 1.0f / l;
    const int ntt = tg >> 7, row = tg & 127;
#pragma unroll
    for (int dt = 0; dt < 2; ++dt) {
      const f32x4 v = dt ? ob : oa;
      const int c = h * 32 + dt * 16 + lg * 4;
      char* tile = attTt + (((size_t)(n * 8 + ntt)) * 4 + (c >> 6)) * 16384;
      bf16x4 pk;
#pragma unroll
      for (int r = 0; r < 4; ++r) pk[r] = (bf16)(v[r] * inv);
      *(bf16x4*)(tile + tb(row, c & 63)) = pk;
    }
  };
  epi(tg0, l0, o0a, o0b);
  epi(tg1, l1, o1a, o1b);
}

// ---------------- kernel 3: output projection (64t x 64o tile, BK=64) ----------------
// 512 blocks (2/CU) for this latency-bound 1-GF GEMM.
__global__ __launch_bounds__(256) void k_proj(const char* __restrict__ attTt,
    const char* __restrict__ Wot, const float* __restrict__ bo, float* __restrict__ out) {
  __shared__ __attribute__((aligned(128))) unsigned char smem[16384]; // A 8K | B 8K
  const int tid = threadIdx.x;
  const int tm = blockIdx.x, om = blockIdx.y, n = blockIdx.z;
  const int w = tid >> 6, lane = tid & 63, lrow = lane & 15, lg = lane >> 4;
  const int wm = (w >> 1) * 32, wn = (w & 1) * 32;
  const char* gA = attTt + ((size_t)(n * 8 + (tm >> 1))) * 65536 + (tm & 1) * 8192;
  const char* gB = Wot + (size_t)(om >> 1) * 65536 + (om & 1) * 8192;

  f32x4 acc[2][2] = {};
#pragma unroll 1
  for (int kk = 0; kk < 4; ++kk) {
    stage8k(gA + kk * 16384, (char*)smem, tid);
    stage8k(gB + kk * 16384, (char*)smem + 8192, tid);
    __syncthreads();
    const char* As = (const char*)smem;
    const char* Bs = As + 8192;
    bf16x8 af[2][2], bv[2][2];
#pragma unroll
    for (int mi = 0; mi < 2; ++mi)
#pragma unroll
      for (int kh = 0; kh < 2; ++kh)
        af[mi][kh] = *(const bf16x8*)(As + tb(wm + mi * 16 + lrow, kh * 32 + lg * 8));
#pragma unroll
    for (int ni = 0; ni < 2; ++ni)
#pragma unroll
      for (int kh = 0; kh < 2; ++kh)
        bv[ni][kh] = *(const bf16x8*)(Bs + tb(wn + ni * 16 + lrow, kh * 32 + lg * 8));
#pragma unroll
    for (int kh = 0; kh < 2; ++kh)
#pragma unroll
      for (int mi = 0; mi < 2; ++mi)
#pragma unroll
        for (int ni = 0; ni < 2; ++ni)
          acc[mi][ni] = __builtin_amdgcn_mfma_f32_16x16x32_bf16(af[mi][kh], bv[ni][kh], acc[mi][ni], 0, 0, 0);
    __syncthreads();
  }

  // epilogue: t = tm*64 + wm + mi*16 + lg*4 + r ; o = om*64 + wn + ni*16 + lrow
  const int t0b = tm * 64 + wm + lg * 4;
  const int ob = om * 64 + wn + lrow;
#pragma unroll
  for (int mi = 0; mi < 2; ++mi) {
    const int t0 = t0b + mi * 16;
#pragma unroll
    for (int ni = 0; ni < 2; ++ni) {
      const int o = ob + ni * 16;
      const float bb = bo[o];
      f32x4 v = acc[mi][ni];
      v[0] += bb; v[1] += bb; v[2] += bb; v[3] += bb;
      *(f32x4*)(out + ((size_t)(n * C_DIM + o)) * T_DIM + t0) = v;
    }
  }
}

extern "C" void kernel_launch(void* const* d_in, const int* in_sizes, int n_in,
                              void* d_out, int out_size, void* d_ws, size_t ws_size,
                              hipStream_t stream) {
  const float* x   = (const float*)d_in[0];
  const float* Wq  = (const float*)d_in[1];
  const float* bq  = (const float*)d_in[2];
  const float* Wkv = (const float*)d_in[3];
  const float* bkv = (const float*)d_in[4];
  const float* Wo  = (const float*)d_in[5];
  const float* bo  = (const float*)d_in[6];
  float* out = (float*)d_out;

  char* ws = (char*)d_ws;
  char* xTt   = ws;                      // 4 MB   [8][8][4][16KB]
  char* Wbt   = ws + (4u  << 20);        // 640 KB [10][4][16KB]
  char* Wot   = ws + (5u  << 20);        // 128 KB [2][4][16KB]
  bf16* q_ws  = (bf16*)(ws + (6u << 20)); // 8 MB  [64][1024][64]
  char* Kt    = ws + (14u << 20);        // 8 MB   [64][16][8KB]
  char* Vt    = ws + (22u << 20);        // 4 MB   [64][16][4KB]
  char* attTt = ws + (26u << 20);        // 4 MB   [8][8][4][16KB]

  k_prep<<<536, 256, 0, stream>>>(x, Wq, Wkv, Wo, xTt, Wbt, Wot);
  k_qkv<<<dim3(8, 10, 8), 256, 0, stream>>>(Wbt, xTt, bq, bkv, q_ws, Kt, Vt);
  k_attn<<<dim3(64, 8), 256, 0, stream>>>(q_ws, Kt, Vt, attTt);
  k_proj<<<dim3(16, 4, 8), 256, 0, stream>>>(attTt, Wot, bo, out);
}